// Round 1
// baseline (1194.530 us; speedup 1.0000x reference)
//
#include <hip/hip_runtime.h>
#include <math.h>

#define BB 32
#define TT 512
#define DW 128
#define DC 64
#define DD 192
#define HH 128
#define G4 512
#define LL 32

__device__ __forceinline__ float sigf(float x) { return 1.f / (1.f + expf(-x)); }

// ---------------------------------------------------------------------------
// K1: fused embedding-gather + input projection GEMM.
// C[n, c] = concat(wordemb[word[n]], charemb[char[n]]) . W_ih_dir[g,:] + b_dir[g]
// n = b*T + t (16384 rows), c in [0,1024): c<512 -> forward dir, else backward.
// Output layout xp_dir[t][b][512] (what the scan wants).
// ---------------------------------------------------------------------------
__global__ __launch_bounds__(256) void k_inproj(
    const int* __restrict__ word, const int* __restrict__ charr,
    const float* __restrict__ wemb, const float* __restrict__ cemb,
    const float* __restrict__ Wf, const float* __restrict__ bf,
    const float* __restrict__ Wb, const float* __restrict__ bb,
    float* __restrict__ xpf, float* __restrict__ xpb)
{
    __shared__ __align__(16) float As[8][132];
    __shared__ __align__(16) float Bs[8][132];
    const int tid = threadIdx.x;
    const int ntile = blockIdx.x;           // 0..127 (token tiles of 128)
    const int ctile = blockIdx.y;           // 0..7   (col tiles of 128)
    const int dir = ctile >> 2;
    const float* W = dir ? Wb : Wf;
    const float* bias = dir ? bb : bf;
    float* xp = dir ? xpb : xpf;
    const int colbase = (ctile & 3) * 128;  // column base within the 512

    const int tr = tid >> 4;    // 0..15
    const int tc = tid & 15;    // 0..15

    float acc[8][8];
#pragma unroll
    for (int i = 0; i < 8; ++i)
#pragma unroll
        for (int j = 0; j < 8; ++j) acc[i][j] = 0.f;

    const int lrow = tid >> 1;            // 0..127: A row (token) and B col (gate) this thread stages
    const int lk   = (tid & 1) * 4;       // 0 or 4
    const int nA   = ntile * 128 + lrow;  // global token index
    const int wi   = word[nA];
    const int ci   = charr[nA];
    const int g    = colbase + lrow;      // gate column this thread stages

    for (int kc = 0; kc < 24; ++kc) {
        const int k0 = kc * 8 + lk;
        float4 av;
        if (k0 < DW) av = *(const float4*)(wemb + (size_t)wi * DW + k0);
        else         av = *(const float4*)(cemb + (size_t)ci * DC + (k0 - DW));
        const float4 bv = *(const float4*)(W + (size_t)g * DD + k0);
        __syncthreads();
        As[lk + 0][lrow] = av.x; As[lk + 1][lrow] = av.y;
        As[lk + 2][lrow] = av.z; As[lk + 3][lrow] = av.w;
        Bs[lk + 0][lrow] = bv.x; Bs[lk + 1][lrow] = bv.y;
        Bs[lk + 2][lrow] = bv.z; Bs[lk + 3][lrow] = bv.w;
        __syncthreads();
#pragma unroll
        for (int kk = 0; kk < 8; ++kk) {
            const float4 a0 = *(const float4*)&As[kk][tr * 8];
            const float4 a1 = *(const float4*)&As[kk][tr * 8 + 4];
            const float4 b0 = *(const float4*)&Bs[kk][tc * 8];
            const float4 b1 = *(const float4*)&Bs[kk][tc * 8 + 4];
            const float a[8]  = {a0.x, a0.y, a0.z, a0.w, a1.x, a1.y, a1.z, a1.w};
            const float bb_[8] = {b0.x, b0.y, b0.z, b0.w, b1.x, b1.y, b1.z, b1.w};
#pragma unroll
            for (int i = 0; i < 8; ++i)
#pragma unroll
                for (int j = 0; j < 8; ++j) acc[i][j] += a[i] * bb_[j];
        }
    }
#pragma unroll
    for (int i = 0; i < 8; ++i) {
        const int n  = ntile * 128 + tr * 8 + i;
        const int b_ = n >> 9, t_ = n & 511;
        float* dst = xp + ((size_t)(t_ * BB + b_)) * G4 + colbase + tc * 8;
#pragma unroll
        for (int j = 0; j < 8; ++j) dst[j] = acc[i][j] + bias[colbase + tc * 8 + j];
    }
}

// ---------------------------------------------------------------------------
// K2: LSTM scan. 64 blocks = (dir, sample). 1024 threads: 2 threads per gate
// column, each holding 64 f32 of W_hh[col,:] in registers. h in LDS.
// ---------------------------------------------------------------------------
__global__ __launch_bounds__(1024) void k_lstm(
    const float* __restrict__ xpf, const float* __restrict__ xpb,
    const float* __restrict__ Whf, const float* __restrict__ Whb,
    float* __restrict__ hf, float* __restrict__ hb)
{
    __shared__ __align__(16) float hs[HH];
    __shared__ __align__(16) float gs[G4];
    const int tid = threadIdx.x;
    const int dir = blockIdx.x >> 5;
    const int b_  = blockIdx.x & 31;
    const float* xp = dir ? xpb : xpf;
    const float* Wh = dir ? Whb : Whf;
    float* hout = dir ? hb : hf;
    const int col = tid >> 1;
    const int kh  = tid & 1;

    float4 w[16];
    const float* wsrc = Wh + (size_t)col * HH + kh * 64;
#pragma unroll
    for (int q = 0; q < 16; ++q) w[q] = *(const float4*)(wsrc + q * 4);

    float c = 0.f;
    if (tid < HH) hs[tid] = 0.f;
    __syncthreads();

    for (int s = 0; s < TT; ++s) {
        const int t = dir ? (TT - 1 - s) : s;
        float p = 0.f;
#pragma unroll
        for (int q = 0; q < 16; ++q) {
            const float4 hv = *(const float4*)&hs[kh * 64 + q * 4];
            p += hv.x * w[q].x; p += hv.y * w[q].y;
            p += hv.z * w[q].z; p += hv.w * w[q].w;
        }
        p += __shfl_xor(p, 1);
        if (kh == 0) gs[col] = p + xp[((size_t)t * BB + b_) * G4 + col];
        __syncthreads();
        if (tid < HH) {
            const float gi = gs[tid], gf = gs[HH + tid];
            const float gg = gs[2 * HH + tid], go = gs[3 * HH + tid];
            c = sigf(gf) * c + sigf(gi) * tanhf(gg);
            const float hv = sigf(go) * tanhf(c);
            hs[tid] = hv;
            hout[((size_t)t * BB + b_) * HH + tid] = hv;
        }
        __syncthreads();
    }
}

// ---------------------------------------------------------------------------
// K3: emit[t][b][l] = (concat(hf,hb)[t][b][:] . W_out[l,:] + b_out[l]) * mask
// ---------------------------------------------------------------------------
__global__ __launch_bounds__(1024) void k_emit(
    const float* __restrict__ hf, const float* __restrict__ hb,
    const float* __restrict__ Wout, const float* __restrict__ bout,
    const int* __restrict__ charr, float* __restrict__ emit)
{
    __shared__ __align__(16) float hsm[BB * 256];
    __shared__ __align__(16) float wsm[LL * 260];
    const int t = blockIdx.x;
    const int tid = threadIdx.x;
    for (int idx = tid; idx < BB * 256; idx += 1024) {
        const int b_ = idx >> 8, u = idx & 255;
        hsm[idx] = (u < HH) ? hf[((size_t)t * BB + b_) * HH + u]
                            : hb[((size_t)t * BB + b_) * HH + (u - HH)];
    }
    for (int idx = tid; idx < LL * 256; idx += 1024) {
        const int l = idx >> 8, u = idx & 255;
        wsm[l * 260 + u] = Wout[idx];
    }
    __syncthreads();
    const int b_ = tid >> 5, l = tid & 31;
    float acc = bout[l];
#pragma unroll 8
    for (int q = 0; q < 64; ++q) {
        const float4 h4 = *(const float4*)&hsm[b_ * 256 + q * 4];
        const float4 w4 = *(const float4*)&wsm[l * 260 + q * 4];
        acc += h4.x * w4.x + h4.y * w4.y + h4.z * w4.z + h4.w * w4.w;
    }
    const float m = (charr[b_ * TT + t] > 0) ? 1.f : 0.f;
    emit[((size_t)t * BB + b_) * LL + l] = acc * m;
}

// ---------------------------------------------------------------------------
// K4: CRF forward. 16 blocks x 64 threads (1 wave = 2 samples). All-register,
// shuffle-based, exp(trans) precomputed, emit prefetched one step ahead.
// ---------------------------------------------------------------------------
__global__ __launch_bounds__(64) void k_crf(
    const float* __restrict__ emit, const int* __restrict__ charr,
    const float* __restrict__ trans, const float* __restrict__ startv,
    const float* __restrict__ endv, float* __restrict__ logZ)
{
    const int tid = threadIdx.x;             // 0..63
    const int b_ = blockIdx.x * 2 + (tid >> 5);
    const int j = tid & 31;
    const int base = tid & 32;               // shfl base of this 32-lane half
    float et[32];
#pragma unroll
    for (int i = 0; i < 32; ++i) et[i] = expf(trans[i * LL + j]);

    float a = startv[j] + emit[(size_t)b_ * LL + j];
    float e_nx = emit[((size_t)1 * BB + b_) * LL + j];
    int   m_nx = charr[b_ * TT + 1];

    for (int t = 1; t < TT; ++t) {
        const float e_cur = e_nx;
        const int   m_cur = m_nx;
        if (t + 1 < TT) {
            e_nx = emit[((size_t)(t + 1) * BB + b_) * LL + j];
            m_nx = charr[b_ * TT + t + 1];
        }
        float M = a;
        M = fmaxf(M, __shfl_xor(M, 16));
        M = fmaxf(M, __shfl_xor(M, 8));
        M = fmaxf(M, __shfl_xor(M, 4));
        M = fmaxf(M, __shfl_xor(M, 2));
        M = fmaxf(M, __shfl_xor(M, 1));
        const float ea = expf(a - M);
        float s0 = 0.f, s1 = 0.f, s2 = 0.f, s3 = 0.f;
#pragma unroll
        for (int i = 0; i < 32; i += 4) {
            s0 += __shfl(ea, base + i    ) * et[i];
            s1 += __shfl(ea, base + i + 1) * et[i + 1];
            s2 += __shfl(ea, base + i + 2) * et[i + 2];
            s3 += __shfl(ea, base + i + 3) * et[i + 3];
        }
        const float anew = M + logf((s0 + s1) + (s2 + s3)) + e_cur;
        a = (m_cur > 0) ? anew : a;
    }
    float z = a + endv[j];
    float M = z;
    M = fmaxf(M, __shfl_xor(M, 16));
    M = fmaxf(M, __shfl_xor(M, 8));
    M = fmaxf(M, __shfl_xor(M, 4));
    M = fmaxf(M, __shfl_xor(M, 2));
    M = fmaxf(M, __shfl_xor(M, 1));
    float sz = expf(z - M);
    sz += __shfl_xor(sz, 16);
    sz += __shfl_xor(sz, 8);
    sz += __shfl_xor(sz, 4);
    sz += __shfl_xor(sz, 2);
    sz += __shfl_xor(sz, 1);
    if (j == 0) logZ[b_] = M + logf(sz);
}

// ---------------------------------------------------------------------------
// K5: gold path score + final output scalar.
// ---------------------------------------------------------------------------
__global__ __launch_bounds__(1024) void k_gold(
    const float* __restrict__ emit, const int* __restrict__ charr,
    const int* __restrict__ y, const float* __restrict__ trans,
    const float* __restrict__ startv, const float* __restrict__ endv,
    const float* __restrict__ logZ, float* __restrict__ out)
{
    __shared__ float red[BB];
    const int tid = threadIdx.x;
    const int b_ = tid >> 5, l = tid & 31;
    float sc = 0.f;
    int ms = 0;
    for (int t = l; t < TT; t += 32) {
        const int yv = y[b_ * TT + t];
        const int m = (charr[b_ * TT + t] > 0);
        if (m) { sc += emit[((size_t)t * BB + b_) * LL + yv]; ms++; }
        if (t + 1 < TT) {
            const int mn = (charr[b_ * TT + t + 1] > 0);
            if (mn) sc += trans[yv * LL + y[b_ * TT + t + 1]];
        }
    }
#pragma unroll
    for (int o = 16; o; o >>= 1) {
        sc += __shfl_xor(sc, o);
        ms += __shfl_xor(ms, o);
    }
    if (l == 0) {
        int last = ms - 1;
        if (last < 0) last = 0;
        const float gold = startv[y[b_ * TT]] + sc + endv[y[b_ * TT + last]];
        red[b_] = logZ[b_] - gold;
    }
    __syncthreads();
    if (tid == 0) {
        float tot = 0.f;
#pragma unroll
        for (int i = 0; i < BB; ++i) tot += red[i];
        out[0] = tot;
    }
}

extern "C" void kernel_launch(void* const* d_in, const int* in_sizes, int n_in,
                              void* d_out, int out_size, void* d_ws, size_t ws_size,
                              hipStream_t stream) {
    (void)in_sizes; (void)n_in; (void)out_size; (void)ws_size;
    const int*   word  = (const int*)d_in[0];
    const int*   charr = (const int*)d_in[1];
    const int*   yv    = (const int*)d_in[2];
    const float* wemb  = (const float*)d_in[3];
    const float* cemb  = (const float*)d_in[4];
    const float* Wihf  = (const float*)d_in[5];
    const float* Whhf  = (const float*)d_in[6];
    const float* bf    = (const float*)d_in[7];
    const float* Wihb  = (const float*)d_in[8];
    const float* Whhb  = (const float*)d_in[9];
    const float* bb    = (const float*)d_in[10];
    const float* Wout  = (const float*)d_in[11];
    const float* bout  = (const float*)d_in[12];
    const float* trans = (const float*)d_in[13];
    const float* startv= (const float*)d_in[14];
    const float* endv  = (const float*)d_in[15];

    float* ws   = (float*)d_ws;
    float* xpf  = ws;                       // [T][B][512]  8,388,608 f
    float* xpb  = xpf + (size_t)TT * BB * G4;
    float* hf   = xpb + (size_t)TT * BB * G4;   // [T][B][128]
    float* hb   = hf + (size_t)TT * BB * HH;
    float* emit = hb + (size_t)TT * BB * HH;    // [T][B][32]
    float* logZ = emit + (size_t)TT * BB * LL;  // [32]

    k_inproj<<<dim3(128, 8), 256, 0, stream>>>(word, charr, wemb, cemb,
                                               Wihf, bf, Wihb, bb, xpf, xpb);
    k_lstm<<<64, 1024, 0, stream>>>(xpf, xpb, Whhf, Whhb, hf, hb);
    k_emit<<<TT, 1024, 0, stream>>>(hf, hb, Wout, bout, charr, emit);
    k_crf<<<16, 64, 0, stream>>>(emit, charr, trans, startv, endv, logZ);
    k_gold<<<1, 1024, 0, stream>>>(emit, charr, yv, trans, startv, endv, logZ,
                                   (float*)d_out);
}

// Round 2
// 771.705 us; speedup vs baseline: 1.5479x; 1.5479x over previous
//
#include <hip/hip_runtime.h>
#include <math.h>

#define BB 32
#define TT 512
#define DW 128
#define DC 64
#define DD 192
#define HH 128
#define G4 512
#define LL 32

__device__ __forceinline__ float fast_sig(float x) {
    return __builtin_amdgcn_rcpf(1.f + __expf(-x));
}
__device__ __forceinline__ float fast_tanh(float x) {
    return 1.f - 2.f * __builtin_amdgcn_rcpf(__expf(2.f * x) + 1.f);
}
// quad_perm lane-xor via DPP (VALU, not LDS)
__device__ __forceinline__ float qxor1(float x) {
    return __int_as_float(__builtin_amdgcn_update_dpp(0, __float_as_int(x), 0xB1, 0xF, 0xF, true));
}
__device__ __forceinline__ float qxor2(float x) {
    return __int_as_float(__builtin_amdgcn_update_dpp(0, __float_as_int(x), 0x4E, 0xF, 0xF, true));
}

// ---------------------------------------------------------------------------
// K1: fused embedding-gather + input projection GEMM (unchanged from R1).
// ---------------------------------------------------------------------------
__global__ __launch_bounds__(256) void k_inproj(
    const int* __restrict__ word, const int* __restrict__ charr,
    const float* __restrict__ wemb, const float* __restrict__ cemb,
    const float* __restrict__ Wf, const float* __restrict__ bf,
    const float* __restrict__ Wb, const float* __restrict__ bb,
    float* __restrict__ xpf, float* __restrict__ xpb)
{
    __shared__ __align__(16) float As[8][132];
    __shared__ __align__(16) float Bs[8][132];
    const int tid = threadIdx.x;
    const int ntile = blockIdx.x;           // 0..127 (token tiles of 128)
    const int ctile = blockIdx.y;           // 0..7   (col tiles of 128)
    const int dir = ctile >> 2;
    const float* W = dir ? Wb : Wf;
    const float* bias = dir ? bb : bf;
    float* xp = dir ? xpb : xpf;
    const int colbase = (ctile & 3) * 128;

    const int tr = tid >> 4;    // 0..15
    const int tc = tid & 15;    // 0..15

    float acc[8][8];
#pragma unroll
    for (int i = 0; i < 8; ++i)
#pragma unroll
        for (int j = 0; j < 8; ++j) acc[i][j] = 0.f;

    const int lrow = tid >> 1;
    const int lk   = (tid & 1) * 4;
    const int nA   = ntile * 128 + lrow;
    const int wi   = word[nA];
    const int ci   = charr[nA];
    const int g    = colbase + lrow;

    for (int kc = 0; kc < 24; ++kc) {
        const int k0 = kc * 8 + lk;
        float4 av;
        if (k0 < DW) av = *(const float4*)(wemb + (size_t)wi * DW + k0);
        else         av = *(const float4*)(cemb + (size_t)ci * DC + (k0 - DW));
        const float4 bv = *(const float4*)(W + (size_t)g * DD + k0);
        __syncthreads();
        As[lk + 0][lrow] = av.x; As[lk + 1][lrow] = av.y;
        As[lk + 2][lrow] = av.z; As[lk + 3][lrow] = av.w;
        Bs[lk + 0][lrow] = bv.x; Bs[lk + 1][lrow] = bv.y;
        Bs[lk + 2][lrow] = bv.z; Bs[lk + 3][lrow] = bv.w;
        __syncthreads();
#pragma unroll
        for (int kk = 0; kk < 8; ++kk) {
            const float4 a0 = *(const float4*)&As[kk][tr * 8];
            const float4 a1 = *(const float4*)&As[kk][tr * 8 + 4];
            const float4 b0 = *(const float4*)&Bs[kk][tc * 8];
            const float4 b1 = *(const float4*)&Bs[kk][tc * 8 + 4];
            const float a[8]  = {a0.x, a0.y, a0.z, a0.w, a1.x, a1.y, a1.z, a1.w};
            const float bb_[8] = {b0.x, b0.y, b0.z, b0.w, b1.x, b1.y, b1.z, b1.w};
#pragma unroll
            for (int i = 0; i < 8; ++i)
#pragma unroll
                for (int j = 0; j < 8; ++j) acc[i][j] += a[i] * bb_[j];
        }
    }
#pragma unroll
    for (int i = 0; i < 8; ++i) {
        const int n  = ntile * 128 + tr * 8 + i;
        const int b_ = n >> 9, t_ = n & 511;
        float* dst = xp + ((size_t)(t_ * BB + b_)) * G4 + colbase + tc * 8;
#pragma unroll
        for (int j = 0; j < 8; ++j) dst[j] = acc[i][j] + bias[colbase + tc * 8 + j];
    }
}

// ---------------------------------------------------------------------------
// K2: LSTM scan v3. 64 blocks = (dir, sample), 512 threads.
// Thread (u=tid>>2, ks=tid&3): all 4 gates of unit u over k-quarter ks.
// 128 weight f32 pinned in VGPRs; h double-buffered in bank-padded LDS;
// DPP quad butterfly combines k-partials; ONE barrier per step.
// ---------------------------------------------------------------------------
__global__ __launch_bounds__(512, 2) void k_lstm(
    const float* __restrict__ xpf, const float* __restrict__ xpb,
    const float* __restrict__ Whf, const float* __restrict__ Whb,
    float* __restrict__ hf, float* __restrict__ hb)
{
    __shared__ __align__(16) float hsd[2][144];   // [buf][ks*36 + j], padded
    const int tid = threadIdx.x;
    const int dir = blockIdx.x >> 5;
    const int b_  = blockIdx.x & 31;
    const float* xp = dir ? xpb : xpf;
    const float* Wh = dir ? Whb : Whf;
    float* hout = dir ? hb : hf;
    const int ks = tid & 3;          // k-quarter (32 wide)
    const int u  = tid >> 2;         // hidden unit 0..127

    // W_hh[g*128+u][ks*32 .. +31] for g=0..3 -> 32 float4 = 128 VGPRs
    float4 wv[32];
#pragma unroll
    for (int g = 0; g < 4; ++g)
#pragma unroll
        for (int k = 0; k < 8; ++k)
            wv[g * 8 + k] = *(const float4*)(Wh + (size_t)(g * 128 + u) * HH + ks * 32 + k * 4);
#pragma unroll
    for (int q = 0; q < 32; ++q)
        asm volatile("" : "+v"(wv[q].x), "+v"(wv[q].y), "+v"(wv[q].z), "+v"(wv[q].w));

    const float mk0 = (ks == 0) ? 1.f : 0.f;
    const float mk1 = (ks == 1) ? 1.f : 0.f;
    const float mk2 = (ks == 2) ? 1.f : 0.f;
    const float mk3 = (ks == 3) ? 1.f : 0.f;

    if (tid < 144) hsd[0][tid] = 0.f;
    float c = 0.f;
    const int t0 = dir ? (TT - 1) : 0;
    float xq = xp[((size_t)t0 * BB + b_) * G4 + ks * 128 + u];
    __syncthreads();

    for (int s = 0; s < TT; ++s) {
        const int t = dir ? (TT - 1 - s) : s;
        const int rb = s & 1;
        // fold this thread's xp contribution into its own gate (g == ks)
        float p0 = mk0 * xq, p1 = mk1 * xq, p2 = mk2 * xq, p3 = mk3 * xq;
#pragma unroll
        for (int k = 0; k < 8; ++k) {
            const float4 hv = *(const float4*)&hsd[rb][ks * 36 + k * 4];
            p0 = fmaf(hv.x, wv[k].x,      p0); p0 = fmaf(hv.y, wv[k].y,      p0);
            p0 = fmaf(hv.z, wv[k].z,      p0); p0 = fmaf(hv.w, wv[k].w,      p0);
            p1 = fmaf(hv.x, wv[8 + k].x,  p1); p1 = fmaf(hv.y, wv[8 + k].y,  p1);
            p1 = fmaf(hv.z, wv[8 + k].z,  p1); p1 = fmaf(hv.w, wv[8 + k].w,  p1);
            p2 = fmaf(hv.x, wv[16 + k].x, p2); p2 = fmaf(hv.y, wv[16 + k].y, p2);
            p2 = fmaf(hv.z, wv[16 + k].z, p2); p2 = fmaf(hv.w, wv[16 + k].w, p2);
            p3 = fmaf(hv.x, wv[24 + k].x, p3); p3 = fmaf(hv.y, wv[24 + k].y, p3);
            p3 = fmaf(hv.z, wv[24 + k].z, p3); p3 = fmaf(hv.w, wv[24 + k].w, p3);
        }
        // prefetch next step's xp early (consumed next iteration)
        if (s + 1 < TT) {
            const int tn = dir ? (t - 1) : (t + 1);
            xq = xp[((size_t)tn * BB + b_) * G4 + ks * 128 + u];
        }
        // quad butterfly: sum the 4 k-quarter partials (VALU DPP, no LDS)
        p0 += qxor1(p0); p0 += qxor2(p0);
        p1 += qxor1(p1); p1 += qxor2(p1);
        p2 += qxor1(p2); p2 += qxor2(p2);
        p3 += qxor1(p3); p3 += qxor2(p3);
        // gates: i=p0, f=p1, g=p2, o=p3 (all 4 lanes redundantly; c replicated)
        c = fast_sig(p1) * c + fast_sig(p0) * fast_tanh(p2);
        const float hv = fast_sig(p3) * fast_tanh(c);
        if (ks == 0) {
            hsd[rb ^ 1][(u >> 5) * 36 + (u & 31)] = hv;
            hout[((size_t)t * BB + b_) * HH + u] = hv;
        }
        __syncthreads();
    }
}

// ---------------------------------------------------------------------------
// K3: emit[t][b][l] = (concat(hf,hb)[t][b][:] . W_out[l,:] + b_out[l]) * mask
// ---------------------------------------------------------------------------
__global__ __launch_bounds__(1024) void k_emit(
    const float* __restrict__ hf, const float* __restrict__ hb,
    const float* __restrict__ Wout, const float* __restrict__ bout,
    const int* __restrict__ charr, float* __restrict__ emit)
{
    __shared__ __align__(16) float hsm[BB * 256];
    __shared__ __align__(16) float wsm[LL * 260];
    const int t = blockIdx.x;
    const int tid = threadIdx.x;
    for (int idx = tid; idx < BB * 256; idx += 1024) {
        const int b_ = idx >> 8, u = idx & 255;
        hsm[idx] = (u < HH) ? hf[((size_t)t * BB + b_) * HH + u]
                            : hb[((size_t)t * BB + b_) * HH + (u - HH)];
    }
    for (int idx = tid; idx < LL * 256; idx += 1024) {
        const int l = idx >> 8, u = idx & 255;
        wsm[l * 260 + u] = Wout[idx];
    }
    __syncthreads();
    const int b_ = tid >> 5, l = tid & 31;
    float acc = bout[l];
#pragma unroll 8
    for (int q = 0; q < 64; ++q) {
        const float4 h4 = *(const float4*)&hsm[b_ * 256 + q * 4];
        const float4 w4 = *(const float4*)&wsm[l * 260 + q * 4];
        acc += h4.x * w4.x + h4.y * w4.y + h4.z * w4.z + h4.w * w4.w;
    }
    const float m = (charr[b_ * TT + t] > 0) ? 1.f : 0.f;
    emit[((size_t)t * BB + b_) * LL + l] = acc * m;
}

// ---------------------------------------------------------------------------
// K4: CRF forward (fast-math transcendentals).
// ---------------------------------------------------------------------------
__global__ __launch_bounds__(64) void k_crf(
    const float* __restrict__ emit, const int* __restrict__ charr,
    const float* __restrict__ trans, const float* __restrict__ startv,
    const float* __restrict__ endv, float* __restrict__ logZ)
{
    const int tid = threadIdx.x;             // 0..63
    const int b_ = blockIdx.x * 2 + (tid >> 5);
    const int j = tid & 31;
    const int base = tid & 32;
    float et[32];
#pragma unroll
    for (int i = 0; i < 32; ++i) et[i] = __expf(trans[i * LL + j]);

    float a = startv[j] + emit[(size_t)b_ * LL + j];
    float e_nx = emit[((size_t)1 * BB + b_) * LL + j];
    int   m_nx = charr[b_ * TT + 1];

    for (int t = 1; t < TT; ++t) {
        const float e_cur = e_nx;
        const int   m_cur = m_nx;
        if (t + 1 < TT) {
            e_nx = emit[((size_t)(t + 1) * BB + b_) * LL + j];
            m_nx = charr[b_ * TT + t + 1];
        }
        float M = a;
        M = fmaxf(M, __shfl_xor(M, 16));
        M = fmaxf(M, __shfl_xor(M, 8));
        M = fmaxf(M, __shfl_xor(M, 4));
        M = fmaxf(M, __shfl_xor(M, 2));
        M = fmaxf(M, __shfl_xor(M, 1));
        const float ea = __expf(a - M);
        float s0 = 0.f, s1 = 0.f, s2 = 0.f, s3 = 0.f;
#pragma unroll
        for (int i = 0; i < 32; i += 4) {
            s0 += __shfl(ea, base + i    ) * et[i];
            s1 += __shfl(ea, base + i + 1) * et[i + 1];
            s2 += __shfl(ea, base + i + 2) * et[i + 2];
            s3 += __shfl(ea, base + i + 3) * et[i + 3];
        }
        const float anew = M + __logf((s0 + s1) + (s2 + s3)) + e_cur;
        a = (m_cur > 0) ? anew : a;
    }
    float z = a + endv[j];
    float M = z;
    M = fmaxf(M, __shfl_xor(M, 16));
    M = fmaxf(M, __shfl_xor(M, 8));
    M = fmaxf(M, __shfl_xor(M, 4));
    M = fmaxf(M, __shfl_xor(M, 2));
    M = fmaxf(M, __shfl_xor(M, 1));
    float sz = __expf(z - M);
    sz += __shfl_xor(sz, 16);
    sz += __shfl_xor(sz, 8);
    sz += __shfl_xor(sz, 4);
    sz += __shfl_xor(sz, 2);
    sz += __shfl_xor(sz, 1);
    if (j == 0) logZ[b_] = M + __logf(sz);
}

// ---------------------------------------------------------------------------
// K5: gold path score + final output scalar.
// ---------------------------------------------------------------------------
__global__ __launch_bounds__(1024) void k_gold(
    const float* __restrict__ emit, const int* __restrict__ charr,
    const int* __restrict__ y, const float* __restrict__ trans,
    const float* __restrict__ startv, const float* __restrict__ endv,
    const float* __restrict__ logZ, float* __restrict__ out)
{
    __shared__ float red[BB];
    const int tid = threadIdx.x;
    const int b_ = tid >> 5, l = tid & 31;
    float sc = 0.f;
    int ms = 0;
    for (int t = l; t < TT; t += 32) {
        const int yv = y[b_ * TT + t];
        const int m = (charr[b_ * TT + t] > 0);
        if (m) { sc += emit[((size_t)t * BB + b_) * LL + yv]; ms++; }
        if (t + 1 < TT) {
            const int mn = (charr[b_ * TT + t + 1] > 0);
            if (mn) sc += trans[yv * LL + y[b_ * TT + t + 1]];
        }
    }
#pragma unroll
    for (int o = 16; o; o >>= 1) {
        sc += __shfl_xor(sc, o);
        ms += __shfl_xor(ms, o);
    }
    if (l == 0) {
        int last = ms - 1;
        if (last < 0) last = 0;
        const float gold = startv[y[b_ * TT]] + sc + endv[y[b_ * TT + last]];
        red[b_] = logZ[b_] - gold;
    }
    __syncthreads();
    if (tid == 0) {
        float tot = 0.f;
#pragma unroll
        for (int i = 0; i < BB; ++i) tot += red[i];
        out[0] = tot;
    }
}

extern "C" void kernel_launch(void* const* d_in, const int* in_sizes, int n_in,
                              void* d_out, int out_size, void* d_ws, size_t ws_size,
                              hipStream_t stream) {
    (void)in_sizes; (void)n_in; (void)out_size; (void)ws_size;
    const int*   word  = (const int*)d_in[0];
    const int*   charr = (const int*)d_in[1];
    const int*   yv    = (const int*)d_in[2];
    const float* wemb  = (const float*)d_in[3];
    const float* cemb  = (const float*)d_in[4];
    const float* Wihf  = (const float*)d_in[5];
    const float* Whhf  = (const float*)d_in[6];
    const float* bf    = (const float*)d_in[7];
    const float* Wihb  = (const float*)d_in[8];
    const float* Whhb  = (const float*)d_in[9];
    const float* bb    = (const float*)d_in[10];
    const float* Wout  = (const float*)d_in[11];
    const float* bout  = (const float*)d_in[12];
    const float* trans = (const float*)d_in[13];
    const float* startv= (const float*)d_in[14];
    const float* endv  = (const float*)d_in[15];

    float* ws   = (float*)d_ws;
    float* xpf  = ws;                       // [T][B][512]
    float* xpb  = xpf + (size_t)TT * BB * G4;
    float* hf   = xpb + (size_t)TT * BB * G4;   // [T][B][128]
    float* hb   = hf + (size_t)TT * BB * HH;
    float* emit = hb + (size_t)TT * BB * HH;    // [T][B][32]
    float* logZ = emit + (size_t)TT * BB * LL;  // [32]

    k_inproj<<<dim3(128, 8), 256, 0, stream>>>(word, charr, wemb, cemb,
                                               Wihf, bf, Wihb, bb, xpf, xpb);
    k_lstm<<<64, 512, 0, stream>>>(xpf, xpb, Whhf, Whhb, hf, hb);
    k_emit<<<TT, 1024, 0, stream>>>(hf, hb, Wout, bout, charr, emit);
    k_crf<<<16, 64, 0, stream>>>(emit, charr, trans, startv, endv, logZ);
    k_gold<<<1, 1024, 0, stream>>>(emit, charr, yv, trans, startv, endv, logZ,
                                   (float*)d_out);
}

// Round 3
// 689.622 us; speedup vs baseline: 1.7322x; 1.1190x over previous
//
#include <hip/hip_runtime.h>
#include <math.h>

#define BB 32
#define TT 512
#define DW 128
#define DC 64
#define DD 192
#define HH 128
#define G4 512
#define LL 32

// quad_perm lane-xor via DPP (VALU, not LDS)
__device__ __forceinline__ float qxor1(float x) {
    return __int_as_float(__builtin_amdgcn_update_dpp(0, __float_as_int(x), 0xB1, 0xF, 0xF, true));
}
__device__ __forceinline__ float qxor2(float x) {
    return __int_as_float(__builtin_amdgcn_update_dpp(0, __float_as_int(x), 0x4E, 0xF, 0xF, true));
}
// quad_perm broadcast of lane q (within each quad)
__device__ __forceinline__ float qbcast(float x, int ctrl_imm) {
    // ctrl: 0x00 lane0, 0x55 lane1, 0xAA lane2, 0xFF lane3
    switch (ctrl_imm) {
        case 0: return __int_as_float(__builtin_amdgcn_update_dpp(0, __float_as_int(x), 0x00, 0xF, 0xF, true));
        case 1: return __int_as_float(__builtin_amdgcn_update_dpp(0, __float_as_int(x), 0x55, 0xF, 0xF, true));
        case 2: return __int_as_float(__builtin_amdgcn_update_dpp(0, __float_as_int(x), 0xAA, 0xF, 0xF, true));
        default:return __int_as_float(__builtin_amdgcn_update_dpp(0, __float_as_int(x), 0xFF, 0xF, 0xF, true));
    }
}

// ---------------------------------------------------------------------------
// K1: fused embedding-gather + input projection GEMM (unchanged).
// ---------------------------------------------------------------------------
__global__ __launch_bounds__(256) void k_inproj(
    const int* __restrict__ word, const int* __restrict__ charr,
    const float* __restrict__ wemb, const float* __restrict__ cemb,
    const float* __restrict__ Wf, const float* __restrict__ bf,
    const float* __restrict__ Wb, const float* __restrict__ bb,
    float* __restrict__ xpf, float* __restrict__ xpb)
{
    __shared__ __align__(16) float As[8][132];
    __shared__ __align__(16) float Bs[8][132];
    const int tid = threadIdx.x;
    const int ntile = blockIdx.x;
    const int ctile = blockIdx.y;
    const int dir = ctile >> 2;
    const float* W = dir ? Wb : Wf;
    const float* bias = dir ? bb : bf;
    float* xp = dir ? xpb : xpf;
    const int colbase = (ctile & 3) * 128;

    const int tr = tid >> 4;
    const int tc = tid & 15;

    float acc[8][8];
#pragma unroll
    for (int i = 0; i < 8; ++i)
#pragma unroll
        for (int j = 0; j < 8; ++j) acc[i][j] = 0.f;

    const int lrow = tid >> 1;
    const int lk   = (tid & 1) * 4;
    const int nA   = ntile * 128 + lrow;
    const int wi   = word[nA];
    const int ci   = charr[nA];
    const int g    = colbase + lrow;

    for (int kc = 0; kc < 24; ++kc) {
        const int k0 = kc * 8 + lk;
        float4 av;
        if (k0 < DW) av = *(const float4*)(wemb + (size_t)wi * DW + k0);
        else         av = *(const float4*)(cemb + (size_t)ci * DC + (k0 - DW));
        const float4 bv = *(const float4*)(W + (size_t)g * DD + k0);
        __syncthreads();
        As[lk + 0][lrow] = av.x; As[lk + 1][lrow] = av.y;
        As[lk + 2][lrow] = av.z; As[lk + 3][lrow] = av.w;
        Bs[lk + 0][lrow] = bv.x; Bs[lk + 1][lrow] = bv.y;
        Bs[lk + 2][lrow] = bv.z; Bs[lk + 3][lrow] = bv.w;
        __syncthreads();
#pragma unroll
        for (int kk = 0; kk < 8; ++kk) {
            const float4 a0 = *(const float4*)&As[kk][tr * 8];
            const float4 a1 = *(const float4*)&As[kk][tr * 8 + 4];
            const float4 b0 = *(const float4*)&Bs[kk][tc * 8];
            const float4 b1 = *(const float4*)&Bs[kk][tc * 8 + 4];
            const float a[8]  = {a0.x, a0.y, a0.z, a0.w, a1.x, a1.y, a1.z, a1.w};
            const float bb_[8] = {b0.x, b0.y, b0.z, b0.w, b1.x, b1.y, b1.z, b1.w};
#pragma unroll
            for (int i = 0; i < 8; ++i)
#pragma unroll
                for (int j = 0; j < 8; ++j) acc[i][j] += a[i] * bb_[j];
        }
    }
#pragma unroll
    for (int i = 0; i < 8; ++i) {
        const int n  = ntile * 128 + tr * 8 + i;
        const int b_ = n >> 9, t_ = n & 511;
        float* dst = xp + ((size_t)(t_ * BB + b_)) * G4 + colbase + tc * 8;
#pragma unroll
        for (int j = 0; j < 8; ++j) dst[j] = acc[i][j] + bias[colbase + tc * 8 + j];
    }
}

// ---------------------------------------------------------------------------
// K2: LSTM scan v4. 64 blocks = (dir, sample), 512 threads.
// Thread (u=tid>>2, ks=tid&3). amdgpu_waves_per_eu(2,2) -> 256-VGPR budget so
// the 32 float4 weights stay resident. Gate nonlinearities DISTRIBUTED across
// the quad (lane ks computes gate ks only) then regathered via quad_perm.
// ---------------------------------------------------------------------------
__global__ __launch_bounds__(512)
__attribute__((amdgpu_waves_per_eu(2, 2)))
void k_lstm(
    const float* __restrict__ xpf, const float* __restrict__ xpb,
    const float* __restrict__ Whf, const float* __restrict__ Whb,
    float* __restrict__ hf, float* __restrict__ hb)
{
    __shared__ __align__(16) float hsd[2][144];   // [buf][(u>>5)*36 + (u&31)]
    const int tid = threadIdx.x;
    const int dir = blockIdx.x >> 5;
    const int b_  = blockIdx.x & 31;
    const float* xp = dir ? xpb : xpf;
    const float* Wh = dir ? Whb : Whf;
    float* hout = dir ? hb : hf;
    const int ks = tid & 3;          // k-quarter (32 wide) == owned gate id
    const int u  = tid >> 2;         // hidden unit 0..127

    // W_hh[g*128+u][ks*32 .. +31] for g=0..3 -> 32 float4 = 128 VGPRs
    float4 wv[32];
#pragma unroll
    for (int g = 0; g < 4; ++g)
#pragma unroll
        for (int k = 0; k < 8; ++k)
            wv[g * 8 + k] = *(const float4*)(Wh + (size_t)(g * 128 + u) * HH + ks * 32 + k * 4);
#pragma unroll
    for (int q = 0; q < 32; ++q)
        asm volatile("" : "+v"(wv[q].x), "+v"(wv[q].y), "+v"(wv[q].z), "+v"(wv[q].w));

    const float mk0 = (ks == 0) ? 1.f : 0.f;
    const float mk1 = (ks == 1) ? 1.f : 0.f;
    const float mk2 = (ks == 2) ? 1.f : 0.f;
    const float mk3 = (ks == 3) ? 1.f : 0.f;
    // unified gate nonlinearity: val = GC0 + GC1 * rcp(1 + exp(GS * p))
    // sigmoid (ks 0,1,3): GS=-1, GC0=0, GC1=1 ; tanh (ks 2): GS=2, GC0=1, GC1=-2
    const bool istanh = (ks == 2);
    const float GS  = istanh ? 2.f : -1.f;
    const float GC0 = istanh ? 1.f : 0.f;
    const float GC1 = istanh ? -2.f : 1.f;

    if (tid < 144) hsd[0][tid] = 0.f;
    float c = 0.f;
    int t = dir ? (TT - 1) : 0;
    const int tstep = dir ? -1 : 1;
    float xq = xp[((size_t)t * BB + b_) * G4 + ks * 128 + u];
    __syncthreads();

    for (int s = 0; s < TT; ++s) {
        const int rb = s & 1;
        // fold this thread's xp contribution into its own gate (g == ks)
        float p0 = mk0 * xq, p1 = mk1 * xq, p2 = mk2 * xq, p3 = mk3 * xq;
        // prefetch next step's xp NOW -> latency hidden under the FMA loop.
        // (one-past-end prefetch lands in the adjacent ws buffer; value unused)
        xq = xp[((size_t)(t + tstep) * BB + b_) * G4 + ks * 128 + u];
#pragma unroll
        for (int k = 0; k < 8; ++k) {
            const float4 hv = *(const float4*)&hsd[rb][ks * 36 + k * 4];
            p0 = fmaf(hv.x, wv[k].x,      p0); p0 = fmaf(hv.y, wv[k].y,      p0);
            p0 = fmaf(hv.z, wv[k].z,      p0); p0 = fmaf(hv.w, wv[k].w,      p0);
            p1 = fmaf(hv.x, wv[8 + k].x,  p1); p1 = fmaf(hv.y, wv[8 + k].y,  p1);
            p1 = fmaf(hv.z, wv[8 + k].z,  p1); p1 = fmaf(hv.w, wv[8 + k].w,  p1);
            p2 = fmaf(hv.x, wv[16 + k].x, p2); p2 = fmaf(hv.y, wv[16 + k].y, p2);
            p2 = fmaf(hv.z, wv[16 + k].z, p2); p2 = fmaf(hv.w, wv[16 + k].w, p2);
            p3 = fmaf(hv.x, wv[24 + k].x, p3); p3 = fmaf(hv.y, wv[24 + k].y, p3);
            p3 = fmaf(hv.z, wv[24 + k].z, p3); p3 = fmaf(hv.w, wv[24 + k].w, p3);
        }
        // quad butterfly: every lane ends with ALL four complete gate sums
        p0 += qxor1(p0); p0 += qxor2(p0);
        p1 += qxor1(p1); p1 += qxor2(p1);
        p2 += qxor1(p2); p2 += qxor2(p2);
        p3 += qxor1(p3); p3 += qxor2(p3);
        // lane ks computes ONLY its gate's nonlinearity (4 trans ops/thread
        // instead of 10), then quad_perm regather.
        const float psel = p0 * mk0 + p1 * mk1 + p2 * mk2 + p3 * mk3;
        const float val  = GC0 + GC1 * __builtin_amdgcn_rcpf(1.f + __expf(GS * psel));
        const float gi = qbcast(val, 0);
        const float gf = qbcast(val, 1);
        const float gg = qbcast(val, 2);
        const float go = qbcast(val, 3);
        c = gf * c + gi * gg;
        const float tc = 1.f - 2.f * __builtin_amdgcn_rcpf(1.f + __expf(2.f * c));
        const float hv = go * tc;
        if (ks == 0) {
            hsd[rb ^ 1][(u >> 5) * 36 + (u & 31)] = hv;
            hout[((size_t)t * BB + b_) * HH + u] = hv;
        }
        t += tstep;
        __syncthreads();
    }
}

// ---------------------------------------------------------------------------
// K3: emit[t][b][l] = (concat(hf,hb)[t][b][:] . W_out[l,:] + b_out[l]) * mask
// ---------------------------------------------------------------------------
__global__ __launch_bounds__(1024) void k_emit(
    const float* __restrict__ hf, const float* __restrict__ hb,
    const float* __restrict__ Wout, const float* __restrict__ bout,
    const int* __restrict__ charr, float* __restrict__ emit)
{
    __shared__ __align__(16) float hsm[BB * 256];
    __shared__ __align__(16) float wsm[LL * 260];
    const int t = blockIdx.x;
    const int tid = threadIdx.x;
    for (int idx = tid; idx < BB * 256; idx += 1024) {
        const int b_ = idx >> 8, u = idx & 255;
        hsm[idx] = (u < HH) ? hf[((size_t)t * BB + b_) * HH + u]
                            : hb[((size_t)t * BB + b_) * HH + (u - HH)];
    }
    for (int idx = tid; idx < LL * 256; idx += 1024) {
        const int l = idx >> 8, u = idx & 255;
        wsm[l * 260 + u] = Wout[idx];
    }
    __syncthreads();
    const int b_ = tid >> 5, l = tid & 31;
    float acc = bout[l];
#pragma unroll 8
    for (int q = 0; q < 64; ++q) {
        const float4 h4 = *(const float4*)&hsm[b_ * 256 + q * 4];
        const float4 w4 = *(const float4*)&wsm[l * 260 + q * 4];
        acc += h4.x * w4.x + h4.y * w4.y + h4.z * w4.z + h4.w * w4.w;
    }
    const float m = (charr[b_ * TT + t] > 0) ? 1.f : 0.f;
    emit[((size_t)t * BB + b_) * LL + l] = acc * m;
}

// ---------------------------------------------------------------------------
// K4: CRF forward (fast-math transcendentals).
// ---------------------------------------------------------------------------
__global__ __launch_bounds__(64) void k_crf(
    const float* __restrict__ emit, const int* __restrict__ charr,
    const float* __restrict__ trans, const float* __restrict__ startv,
    const float* __restrict__ endv, float* __restrict__ logZ)
{
    const int tid = threadIdx.x;             // 0..63
    const int b_ = blockIdx.x * 2 + (tid >> 5);
    const int j = tid & 31;
    const int base = tid & 32;
    float et[32];
#pragma unroll
    for (int i = 0; i < 32; ++i) et[i] = __expf(trans[i * LL + j]);

    float a = startv[j] + emit[(size_t)b_ * LL + j];
    float e_nx = emit[((size_t)1 * BB + b_) * LL + j];
    int   m_nx = charr[b_ * TT + 1];

    for (int t = 1; t < TT; ++t) {
        const float e_cur = e_nx;
        const int   m_cur = m_nx;
        if (t + 1 < TT) {
            e_nx = emit[((size_t)(t + 1) * BB + b_) * LL + j];
            m_nx = charr[b_ * TT + t + 1];
        }
        float M = a;
        M = fmaxf(M, __shfl_xor(M, 16));
        M = fmaxf(M, __shfl_xor(M, 8));
        M = fmaxf(M, __shfl_xor(M, 4));
        M = fmaxf(M, __shfl_xor(M, 2));
        M = fmaxf(M, __shfl_xor(M, 1));
        const float ea = __expf(a - M);
        float s0 = 0.f, s1 = 0.f, s2 = 0.f, s3 = 0.f;
#pragma unroll
        for (int i = 0; i < 32; i += 4) {
            s0 += __shfl(ea, base + i    ) * et[i];
            s1 += __shfl(ea, base + i + 1) * et[i + 1];
            s2 += __shfl(ea, base + i + 2) * et[i + 2];
            s3 += __shfl(ea, base + i + 3) * et[i + 3];
        }
        const float anew = M + __logf((s0 + s1) + (s2 + s3)) + e_cur;
        a = (m_cur > 0) ? anew : a;
    }
    float z = a + endv[j];
    float M = z;
    M = fmaxf(M, __shfl_xor(M, 16));
    M = fmaxf(M, __shfl_xor(M, 8));
    M = fmaxf(M, __shfl_xor(M, 4));
    M = fmaxf(M, __shfl_xor(M, 2));
    M = fmaxf(M, __shfl_xor(M, 1));
    float sz = __expf(z - M);
    sz += __shfl_xor(sz, 16);
    sz += __shfl_xor(sz, 8);
    sz += __shfl_xor(sz, 4);
    sz += __shfl_xor(sz, 2);
    sz += __shfl_xor(sz, 1);
    if (j == 0) logZ[b_] = M + __logf(sz);
}

// ---------------------------------------------------------------------------
// K5: gold path score + final output scalar.
// ---------------------------------------------------------------------------
__global__ __launch_bounds__(1024) void k_gold(
    const float* __restrict__ emit, const int* __restrict__ charr,
    const int* __restrict__ y, const float* __restrict__ trans,
    const float* __restrict__ startv, const float* __restrict__ endv,
    const float* __restrict__ logZ, float* __restrict__ out)
{
    __shared__ float red[BB];
    const int tid = threadIdx.x;
    const int b_ = tid >> 5, l = tid & 31;
    float sc = 0.f;
    int ms = 0;
    for (int t = l; t < TT; t += 32) {
        const int yv = y[b_ * TT + t];
        const int m = (charr[b_ * TT + t] > 0);
        if (m) { sc += emit[((size_t)t * BB + b_) * LL + yv]; ms++; }
        if (t + 1 < TT) {
            const int mn = (charr[b_ * TT + t + 1] > 0);
            if (mn) sc += trans[yv * LL + y[b_ * TT + t + 1]];
        }
    }
#pragma unroll
    for (int o = 16; o; o >>= 1) {
        sc += __shfl_xor(sc, o);
        ms += __shfl_xor(ms, o);
    }
    if (l == 0) {
        int last = ms - 1;
        if (last < 0) last = 0;
        const float gold = startv[y[b_ * TT]] + sc + endv[y[b_ * TT + last]];
        red[b_] = logZ[b_] - gold;
    }
    __syncthreads();
    if (tid == 0) {
        float tot = 0.f;
#pragma unroll
        for (int i = 0; i < BB; ++i) tot += red[i];
        out[0] = tot;
    }
}

extern "C" void kernel_launch(void* const* d_in, const int* in_sizes, int n_in,
                              void* d_out, int out_size, void* d_ws, size_t ws_size,
                              hipStream_t stream) {
    (void)in_sizes; (void)n_in; (void)out_size; (void)ws_size;
    const int*   word  = (const int*)d_in[0];
    const int*   charr = (const int*)d_in[1];
    const int*   yv    = (const int*)d_in[2];
    const float* wemb  = (const float*)d_in[3];
    const float* cemb  = (const float*)d_in[4];
    const float* Wihf  = (const float*)d_in[5];
    const float* Whhf  = (const float*)d_in[6];
    const float* bf    = (const float*)d_in[7];
    const float* Wihb  = (const float*)d_in[8];
    const float* Whhb  = (const float*)d_in[9];
    const float* bb    = (const float*)d_in[10];
    const float* Wout  = (const float*)d_in[11];
    const float* bout  = (const float*)d_in[12];
    const float* trans = (const float*)d_in[13];
    const float* startv= (const float*)d_in[14];
    const float* endv  = (const float*)d_in[15];

    float* ws   = (float*)d_ws;
    float* xpf  = ws;                       // [T][B][512]
    float* xpb  = xpf + (size_t)TT * BB * G4;
    float* hf   = xpb + (size_t)TT * BB * G4;   // [T][B][128]
    float* hb   = hf + (size_t)TT * BB * HH;
    float* emit = hb + (size_t)TT * BB * HH;    // [T][B][32]
    float* logZ = emit + (size_t)TT * BB * LL;  // [32]

    k_inproj<<<dim3(128, 8), 256, 0, stream>>>(word, charr, wemb, cemb,
                                               Wihf, bf, Wihb, bb, xpf, xpb);
    k_lstm<<<64, 512, 0, stream>>>(xpf, xpb, Whhf, Whhb, hf, hb);
    k_emit<<<TT, 1024, 0, stream>>>(hf, hb, Wout, bout, charr, emit);
    k_crf<<<16, 64, 0, stream>>>(emit, charr, trans, startv, endv, logZ);
    k_gold<<<1, 1024, 0, stream>>>(emit, charr, yv, trans, startv, endv, logZ,
                                   (float*)d_out);
}

// Round 5
// 555.541 us; speedup vs baseline: 2.1502x; 1.2414x over previous
//
#include <hip/hip_runtime.h>
#include <math.h>

#define BB 32
#define TT 512
#define DW 128
#define DC 64
#define DD 192
#define HH 128
#define G4 512
#define LL 32

typedef __fp16 h2_t __attribute__((ext_vector_type(2)));

// quad_perm lane-xor via DPP (VALU, not LDS)
__device__ __forceinline__ float qxor1(float x) {
    return __int_as_float(__builtin_amdgcn_update_dpp(0, __float_as_int(x), 0xB1, 0xF, 0xF, true));
}
__device__ __forceinline__ float qxor2(float x) {
    return __int_as_float(__builtin_amdgcn_update_dpp(0, __float_as_int(x), 0x4E, 0xF, 0xF, true));
}
// quad_perm broadcast of lane q (within each quad)
__device__ __forceinline__ float qbcast(float x, int ctrl_imm) {
    switch (ctrl_imm) {
        case 0: return __int_as_float(__builtin_amdgcn_update_dpp(0, __float_as_int(x), 0x00, 0xF, 0xF, true));
        case 1: return __int_as_float(__builtin_amdgcn_update_dpp(0, __float_as_int(x), 0x55, 0xF, 0xF, true));
        case 2: return __int_as_float(__builtin_amdgcn_update_dpp(0, __float_as_int(x), 0xAA, 0xF, 0xF, true));
        default:return __int_as_float(__builtin_amdgcn_update_dpp(0, __float_as_int(x), 0xFF, 0xF, 0xF, true));
    }
}

// ---------------------------------------------------------------------------
// K1: fused embedding-gather + input projection GEMM (unchanged).
// ---------------------------------------------------------------------------
__global__ __launch_bounds__(256) void k_inproj(
    const int* __restrict__ word, const int* __restrict__ charr,
    const float* __restrict__ wemb, const float* __restrict__ cemb,
    const float* __restrict__ Wf, const float* __restrict__ bf,
    const float* __restrict__ Wb, const float* __restrict__ bb,
    float* __restrict__ xpf, float* __restrict__ xpb)
{
    __shared__ __align__(16) float As[8][132];
    __shared__ __align__(16) float Bs[8][132];
    const int tid = threadIdx.x;
    const int ntile = blockIdx.x;
    const int ctile = blockIdx.y;
    const int dir = ctile >> 2;
    const float* W = dir ? Wb : Wf;
    const float* bias = dir ? bb : bf;
    float* xp = dir ? xpb : xpf;
    const int colbase = (ctile & 3) * 128;

    const int tr = tid >> 4;
    const int tc = tid & 15;

    float acc[8][8];
#pragma unroll
    for (int i = 0; i < 8; ++i)
#pragma unroll
        for (int j = 0; j < 8; ++j) acc[i][j] = 0.f;

    const int lrow = tid >> 1;
    const int lk   = (tid & 1) * 4;
    const int nA   = ntile * 128 + lrow;
    const int wi   = word[nA];
    const int ci   = charr[nA];
    const int g    = colbase + lrow;

    for (int kc = 0; kc < 24; ++kc) {
        const int k0 = kc * 8 + lk;
        float4 av;
        if (k0 < DW) av = *(const float4*)(wemb + (size_t)wi * DW + k0);
        else         av = *(const float4*)(cemb + (size_t)ci * DC + (k0 - DW));
        const float4 bv = *(const float4*)(W + (size_t)g * DD + k0);
        __syncthreads();
        As[lk + 0][lrow] = av.x; As[lk + 1][lrow] = av.y;
        As[lk + 2][lrow] = av.z; As[lk + 3][lrow] = av.w;
        Bs[lk + 0][lrow] = bv.x; Bs[lk + 1][lrow] = bv.y;
        Bs[lk + 2][lrow] = bv.z; Bs[lk + 3][lrow] = bv.w;
        __syncthreads();
#pragma unroll
        for (int kk = 0; kk < 8; ++kk) {
            const float4 a0 = *(const float4*)&As[kk][tr * 8];
            const float4 a1 = *(const float4*)&As[kk][tr * 8 + 4];
            const float4 b0 = *(const float4*)&Bs[kk][tc * 8];
            const float4 b1 = *(const float4*)&Bs[kk][tc * 8 + 4];
            const float a[8]  = {a0.x, a0.y, a0.z, a0.w, a1.x, a1.y, a1.z, a1.w};
            const float bb_[8] = {b0.x, b0.y, b0.z, b0.w, b1.x, b1.y, b1.z, b1.w};
#pragma unroll
            for (int i = 0; i < 8; ++i)
#pragma unroll
                for (int j = 0; j < 8; ++j) acc[i][j] += a[i] * bb_[j];
        }
    }
#pragma unroll
    for (int i = 0; i < 8; ++i) {
        const int n  = ntile * 128 + tr * 8 + i;
        const int b_ = n >> 9, t_ = n & 511;
        float* dst = xp + ((size_t)(t_ * BB + b_)) * G4 + colbase + tc * 8;
#pragma unroll
        for (int j = 0; j < 8; ++j) dst[j] = acc[i][j] + bias[colbase + tc * 8 + j];
    }
}

// ---------------------------------------------------------------------------
// K2: LSTM scan v5: f16 dot2. 64 blocks = (dir, sample), 512 threads.
// Thread (u=tid>>2, ks=tid&3). Weights converted ONCE to packed half2
// (64 VGPRs; load+cvt chain is not rematerializable -> truly resident).
// h kept in LDS as f16, double-buffered, bank-disjoint padded layout.
// v_dot2_f32_f16 halves the FMA issue floor vs fp32.
// ---------------------------------------------------------------------------
__global__ __launch_bounds__(512)
__attribute__((amdgpu_waves_per_eu(2, 2)))
void k_lstm(
    const float* __restrict__ xpf, const float* __restrict__ xpb,
    const float* __restrict__ Whf, const float* __restrict__ Whb,
    float* __restrict__ hf, float* __restrict__ hb)
{
    // [buf][ks*40 + j] f16 units; per-ks block = 80 B -> bank-quads
    // {0-3},{20-23},{8-11},{28-31} per read -> conflict-free broadcast.
    __shared__ __align__(16) __fp16 hsd[2][160];
    const int tid = threadIdx.x;
    const int dir = blockIdx.x >> 5;
    const int b_  = blockIdx.x & 31;
    const float* xp = dir ? xpb : xpf;
    const float* Wh = dir ? Whb : Whf;
    float* hout = dir ? hb : hf;
    const int ks = tid & 3;          // k-quarter (32 wide) == owned gate id
    const int u  = tid >> 2;         // hidden unit 0..127

    // W_hh[g*128+u][ks*32 .. +31] for g=0..3 as packed half2: 4x16 = 64 VGPRs
    h2_t w2[4][16];
#pragma unroll
    for (int g = 0; g < 4; ++g) {
        const float2* wp = (const float2*)(Wh + (size_t)(g * 128 + u) * HH + ks * 32);
#pragma unroll
        for (int j = 0; j < 16; ++j)
            w2[g][j] = __builtin_amdgcn_cvt_pkrtz(wp[j].x, wp[j].y);
    }

    const float mk0 = (ks == 0) ? 1.f : 0.f;
    const float mk1 = (ks == 1) ? 1.f : 0.f;
    const float mk2 = (ks == 2) ? 1.f : 0.f;
    const float mk3 = (ks == 3) ? 1.f : 0.f;
    // unified gate nonlinearity: val = GC0 + GC1 * rcp(1 + exp(GS * p))
    const bool istanh = (ks == 2);
    const float GS  = istanh ? 2.f : -1.f;
    const float GC0 = istanh ? 1.f : 0.f;
    const float GC1 = istanh ? -2.f : 1.f;

    if (tid < 80) ((unsigned int*)&hsd[0][0])[tid] = 0u;   // zero buffer 0
    float c = 0.f;
    int t = dir ? (TT - 1) : 0;
    const int tstep = dir ? -1 : 1;
    float xq = xp[((long long)t * BB + b_) * G4 + ks * 128 + u];
    __syncthreads();

    for (int s = 0; s < TT; ++s) {
        const int rb = s & 1;
        float p0 = mk0 * xq, p1 = mk1 * xq, p2 = mk2 * xq, p3 = mk3 * xq;
        // prefetch next xp now (one-past-end lands in adjacent ws buffer)
        xq = xp[((long long)(t + tstep) * BB + b_) * G4 + ks * 128 + u];
#pragma unroll
        for (int q = 0; q < 4; ++q) {
            const uint4 hv = *(const uint4*)&hsd[rb][ks * 40 + q * 8];
            const h2_t ha  = __builtin_bit_cast(h2_t, hv.x);
            const h2_t hbv = __builtin_bit_cast(h2_t, hv.y);
            const h2_t hc  = __builtin_bit_cast(h2_t, hv.z);
            const h2_t hd  = __builtin_bit_cast(h2_t, hv.w);
            p0 = __builtin_amdgcn_fdot2(ha,  w2[0][q*4+0], p0, false);
            p0 = __builtin_amdgcn_fdot2(hbv, w2[0][q*4+1], p0, false);
            p0 = __builtin_amdgcn_fdot2(hc,  w2[0][q*4+2], p0, false);
            p0 = __builtin_amdgcn_fdot2(hd,  w2[0][q*4+3], p0, false);
            p1 = __builtin_amdgcn_fdot2(ha,  w2[1][q*4+0], p1, false);
            p1 = __builtin_amdgcn_fdot2(hbv, w2[1][q*4+1], p1, false);
            p1 = __builtin_amdgcn_fdot2(hc,  w2[1][q*4+2], p1, false);
            p1 = __builtin_amdgcn_fdot2(hd,  w2[1][q*4+3], p1, false);
            p2 = __builtin_amdgcn_fdot2(ha,  w2[2][q*4+0], p2, false);
            p2 = __builtin_amdgcn_fdot2(hbv, w2[2][q*4+1], p2, false);
            p2 = __builtin_amdgcn_fdot2(hc,  w2[2][q*4+2], p2, false);
            p2 = __builtin_amdgcn_fdot2(hd,  w2[2][q*4+3], p2, false);
            p3 = __builtin_amdgcn_fdot2(ha,  w2[3][q*4+0], p3, false);
            p3 = __builtin_amdgcn_fdot2(hbv, w2[3][q*4+1], p3, false);
            p3 = __builtin_amdgcn_fdot2(hc,  w2[3][q*4+2], p3, false);
            p3 = __builtin_amdgcn_fdot2(hd,  w2[3][q*4+3], p3, false);
        }
        // quad butterfly: every lane ends with ALL four complete gate sums
        p0 += qxor1(p0); p0 += qxor2(p0);
        p1 += qxor1(p1); p1 += qxor2(p1);
        p2 += qxor1(p2); p2 += qxor2(p2);
        p3 += qxor1(p3); p3 += qxor2(p3);
        // lane ks computes only its gate's nonlinearity, quad_perm regather
        const float psel = p0 * mk0 + p1 * mk1 + p2 * mk2 + p3 * mk3;
        const float val  = GC0 + GC1 * __builtin_amdgcn_rcpf(1.f + __expf(GS * psel));
        const float gi = qbcast(val, 0);
        const float gf = qbcast(val, 1);
        const float gg = qbcast(val, 2);
        const float go = qbcast(val, 3);
        c = gf * c + gi * gg;
        const float tc = 1.f - 2.f * __builtin_amdgcn_rcpf(1.f + __expf(2.f * c));
        const float hv = go * tc;
        if (ks == 0) {
            hsd[rb ^ 1][(u >> 5) * 40 + (u & 31)] = (__fp16)hv;
            hout[((long long)t * BB + b_) * HH + u] = hv;
        }
        t += tstep;
        __syncthreads();
    }
}

// ---------------------------------------------------------------------------
// K3: emit[t][b][l] = (concat(hf,hb)[t][b][:] . W_out[l,:] + b_out[l]) * mask
// ---------------------------------------------------------------------------
__global__ __launch_bounds__(1024) void k_emit(
    const float* __restrict__ hf, const float* __restrict__ hb,
    const float* __restrict__ Wout, const float* __restrict__ bout,
    const int* __restrict__ charr, float* __restrict__ emit)
{
    __shared__ __align__(16) float hsm[BB * 256];
    __shared__ __align__(16) float wsm[LL * 260];
    const int t = blockIdx.x;
    const int tid = threadIdx.x;
    for (int idx = tid; idx < BB * 256; idx += 1024) {
        const int b_ = idx >> 8, u = idx & 255;
        hsm[idx] = (u < HH) ? hf[((size_t)t * BB + b_) * HH + u]
                            : hb[((size_t)t * BB + b_) * HH + (u - HH)];
    }
    for (int idx = tid; idx < LL * 256; idx += 1024) {
        const int l = idx >> 8, u = idx & 255;
        wsm[l * 260 + u] = Wout[idx];
    }
    __syncthreads();
    const int b_ = tid >> 5, l = tid & 31;
    float acc = bout[l];
#pragma unroll 8
    for (int q = 0; q < 64; ++q) {
        const float4 h4 = *(const float4*)&hsm[b_ * 256 + q * 4];
        const float4 w4 = *(const float4*)&wsm[l * 260 + q * 4];
        acc += h4.x * w4.x + h4.y * w4.y + h4.z * w4.z + h4.w * w4.w;
    }
    const float m = (charr[b_ * TT + t] > 0) ? 1.f : 0.f;
    emit[((size_t)t * BB + b_) * LL + l] = acc * m;
}

// ---------------------------------------------------------------------------
// K4: CRF forward v2 — LINEAR-space with periodic renorm.
// ---------------------------------------------------------------------------
__global__ __launch_bounds__(64) void k_crf(
    const float* __restrict__ emit, const int* __restrict__ charr,
    const float* __restrict__ trans, const float* __restrict__ startv,
    const float* __restrict__ endv, float* __restrict__ logZ)
{
    const int tid = threadIdx.x;             // lanes 32..63 mirror lanes 0..31
    const int b_ = blockIdx.x;
    const int j = tid & 31;
    float et[32];
#pragma unroll
    for (int i = 0; i < 32; ++i) et[i] = __expf(trans[i * LL + j]);

    const float a0 = startv[j] + emit[(size_t)b_ * LL + j];
    float M = a0;
    M = fmaxf(M, __shfl_xor(M, 16));
    M = fmaxf(M, __shfl_xor(M, 8));
    M = fmaxf(M, __shfl_xor(M, 4));
    M = fmaxf(M, __shfl_xor(M, 2));
    M = fmaxf(M, __shfl_xor(M, 1));
    float A = __expf(a0 - M);
    float logsc = M;

    float e_nx = emit[((size_t)1 * BB + b_) * LL + j];
    int   m_nx = charr[b_ * TT + 1];

    for (int t = 1; t < TT; ++t) {
        const float ee = __expf(e_nx);       // off critical chain (prefetched)
        const int m_cur = m_nx;
        if (t + 1 < TT) {
            e_nx = emit[((size_t)(t + 1) * BB + b_) * LL + j];
            m_nx = charr[b_ * TT + t + 1];
        }
        float s0 = 0.f, s1 = 0.f, s2 = 0.f, s3 = 0.f;
#pragma unroll
        for (int i = 0; i < 32; i += 4) {
            s0 = fmaf(__shfl(A, i    ), et[i    ], s0);
            s1 = fmaf(__shfl(A, i + 1), et[i + 1], s1);
            s2 = fmaf(__shfl(A, i + 2), et[i + 2], s2);
            s3 = fmaf(__shfl(A, i + 3), et[i + 3], s3);
        }
        const float Anew = ((s0 + s1) + (s2 + s3)) * ee;
        A = (m_cur > 0) ? Anew : A;
        if ((t & 7) == 0) {                  // renorm every 8 steps
            float S = A;
            S = fmaxf(S, __shfl_xor(S, 16));
            S = fmaxf(S, __shfl_xor(S, 8));
            S = fmaxf(S, __shfl_xor(S, 4));
            S = fmaxf(S, __shfl_xor(S, 2));
            S = fmaxf(S, __shfl_xor(S, 1));
            A *= __builtin_amdgcn_rcpf(S);
            logsc += __logf(S);
        }
    }
    // finalize: alpha_j = log(A_j) + logsc; logZ = LSE_j(alpha_j + end_j)
    const float z = __logf(A) + logsc + endv[j];
    float Mz = z;
    Mz = fmaxf(Mz, __shfl_xor(Mz, 16));
    Mz = fmaxf(Mz, __shfl_xor(Mz, 8));
    Mz = fmaxf(Mz, __shfl_xor(Mz, 4));
    Mz = fmaxf(Mz, __shfl_xor(Mz, 2));
    Mz = fmaxf(Mz, __shfl_xor(Mz, 1));
    float sz = __expf(z - Mz);
    sz += __shfl_xor(sz, 16);
    sz += __shfl_xor(sz, 8);
    sz += __shfl_xor(sz, 4);
    sz += __shfl_xor(sz, 2);
    sz += __shfl_xor(sz, 1);
    if (tid == 0) logZ[b_] = Mz + __logf(sz);
}

// ---------------------------------------------------------------------------
// K5: gold path score + final output scalar.
// ---------------------------------------------------------------------------
__global__ __launch_bounds__(1024) void k_gold(
    const float* __restrict__ emit, const int* __restrict__ charr,
    const int* __restrict__ y, const float* __restrict__ trans,
    const float* __restrict__ startv, const float* __restrict__ endv,
    const float* __restrict__ logZ, float* __restrict__ out)
{
    __shared__ float red[BB];
    const int tid = threadIdx.x;
    const int b_ = tid >> 5, l = tid & 31;
    float sc = 0.f;
    int ms = 0;
    for (int t = l; t < TT; t += 32) {
        const int yv = y[b_ * TT + t];
        const int m = (charr[b_ * TT + t] > 0);
        if (m) { sc += emit[((size_t)t * BB + b_) * LL + yv]; ms++; }
        if (t + 1 < TT) {
            const int mn = (charr[b_ * TT + t + 1] > 0);
            if (mn) sc += trans[yv * LL + y[b_ * TT + t + 1]];
        }
    }
#pragma unroll
    for (int o = 16; o; o >>= 1) {
        sc += __shfl_xor(sc, o);
        ms += __shfl_xor(ms, o);
    }
    if (l == 0) {
        int last = ms - 1;
        if (last < 0) last = 0;
        const float gold = startv[y[b_ * TT]] + sc + endv[y[b_ * TT + last]];
        red[b_] = logZ[b_] - gold;
    }
    __syncthreads();
    if (tid == 0) {
        float tot = 0.f;
#pragma unroll
        for (int i = 0; i < BB; ++i) tot += red[i];
        out[0] = tot;
    }
}

extern "C" void kernel_launch(void* const* d_in, const int* in_sizes, int n_in,
                              void* d_out, int out_size, void* d_ws, size_t ws_size,
                              hipStream_t stream) {
    (void)in_sizes; (void)n_in; (void)out_size; (void)ws_size;
    const int*   word  = (const int*)d_in[0];
    const int*   charr = (const int*)d_in[1];
    const int*   yv    = (const int*)d_in[2];
    const float* wemb  = (const float*)d_in[3];
    const float* cemb  = (const float*)d_in[4];
    const float* Wihf  = (const float*)d_in[5];
    const float* Whhf  = (const float*)d_in[6];
    const float* bf    = (const float*)d_in[7];
    const float* Wihb  = (const float*)d_in[8];
    const float* Whhb  = (const float*)d_in[9];
    const float* bb    = (const float*)d_in[10];
    const float* Wout  = (const float*)d_in[11];
    const float* bout  = (const float*)d_in[12];
    const float* trans = (const float*)d_in[13];
    const float* startv= (const float*)d_in[14];
    const float* endv  = (const float*)d_in[15];

    float* ws   = (float*)d_ws;
    float* xpf  = ws;                       // [T][B][512]
    float* xpb  = xpf + (size_t)TT * BB * G4;
    float* hf   = xpb + (size_t)TT * BB * G4;   // [T][B][128]
    float* hb   = hf + (size_t)TT * BB * HH;
    float* emit = hb + (size_t)TT * BB * HH;    // [T][B][32]
    float* logZ = emit + (size_t)TT * BB * LL;  // [32]

    k_inproj<<<dim3(128, 8), 256, 0, stream>>>(word, charr, wemb, cemb,
                                               Wihf, bf, Wihb, bb, xpf, xpb);
    k_lstm<<<64, 512, 0, stream>>>(xpf, xpb, Whhf, Whhb, hf, hb);
    k_emit<<<TT, 1024, 0, stream>>>(hf, hb, Wout, bout, charr, emit);
    k_crf<<<32, 64, 0, stream>>>(emit, charr, trans, startv, endv, logZ);
    k_gold<<<1, 1024, 0, stream>>>(emit, charr, yv, trans, startv, endv, logZ,
                                   (float*)d_out);
}

// Round 6
// 539.082 us; speedup vs baseline: 2.2159x; 1.0305x over previous
//
#include <hip/hip_runtime.h>
#include <math.h>

#define BB 32
#define TT 512
#define DW 128
#define DC 64
#define DD 192
#define HH 128
#define G4 512
#define LL 32

typedef __fp16 h2_t __attribute__((ext_vector_type(2)));

// quad_perm lane-xor via DPP (VALU, not LDS)
__device__ __forceinline__ float qxor1(float x) {
    return __int_as_float(__builtin_amdgcn_update_dpp(0, __float_as_int(x), 0xB1, 0xF, 0xF, true));
}
__device__ __forceinline__ float qxor2(float x) {
    return __int_as_float(__builtin_amdgcn_update_dpp(0, __float_as_int(x), 0x4E, 0xF, 0xF, true));
}
// quad_perm broadcast of lane q (within each quad)
__device__ __forceinline__ float qbcast(float x, int ctrl_imm) {
    switch (ctrl_imm) {
        case 0: return __int_as_float(__builtin_amdgcn_update_dpp(0, __float_as_int(x), 0x00, 0xF, 0xF, true));
        case 1: return __int_as_float(__builtin_amdgcn_update_dpp(0, __float_as_int(x), 0x55, 0xF, 0xF, true));
        case 2: return __int_as_float(__builtin_amdgcn_update_dpp(0, __float_as_int(x), 0xAA, 0xF, 0xF, true));
        default:return __int_as_float(__builtin_amdgcn_update_dpp(0, __float_as_int(x), 0xFF, 0xF, 0xF, true));
    }
}

// ---------------------------------------------------------------------------
// K1: fused embedding-gather + input projection GEMM, f16 dot2 inner loop.
// ---------------------------------------------------------------------------
__global__ __launch_bounds__(256) void k_inproj(
    const int* __restrict__ word, const int* __restrict__ charr,
    const float* __restrict__ wemb, const float* __restrict__ cemb,
    const float* __restrict__ Wf, const float* __restrict__ bf,
    const float* __restrict__ Wb, const float* __restrict__ bb,
    float* __restrict__ xpf, float* __restrict__ xpb)
{
    __shared__ __align__(16) h2_t As2[4][132];   // [k-pair][row]
    __shared__ __align__(16) h2_t Bs2[4][132];   // [k-pair][gate-col]
    const int tid = threadIdx.x;
    const int ntile = blockIdx.x;
    const int ctile = blockIdx.y;
    const int dir = ctile >> 2;
    const float* W = dir ? Wb : Wf;
    const float* bias = dir ? bb : bf;
    float* xp = dir ? xpb : xpf;
    const int colbase = (ctile & 3) * 128;

    const int tr = tid >> 4;    // 0..15
    const int tc = tid & 15;    // 0..15

    float acc[8][8];
#pragma unroll
    for (int i = 0; i < 8; ++i)
#pragma unroll
        for (int j = 0; j < 8; ++j) acc[i][j] = 0.f;

    const int lrow = tid >> 1;            // 0..127
    const int lk   = (tid & 1) * 4;       // 0 or 4
    const int kp0  = lk >> 1;             // 0 or 2
    const int nA   = ntile * 128 + lrow;
    const int wi   = word[nA];
    const int ci   = charr[nA];
    const int g    = colbase + lrow;

    for (int kc = 0; kc < 24; ++kc) {
        const int k0 = kc * 8 + lk;
        float4 av;
        if (k0 < DW) av = *(const float4*)(wemb + (size_t)wi * DW + k0);
        else         av = *(const float4*)(cemb + (size_t)ci * DC + (k0 - DW));
        const float4 bv = *(const float4*)(W + (size_t)g * DD + k0);
        __syncthreads();
        As2[kp0 + 0][lrow] = __builtin_amdgcn_cvt_pkrtz(av.x, av.y);
        As2[kp0 + 1][lrow] = __builtin_amdgcn_cvt_pkrtz(av.z, av.w);
        Bs2[kp0 + 0][lrow] = __builtin_amdgcn_cvt_pkrtz(bv.x, bv.y);
        Bs2[kp0 + 1][lrow] = __builtin_amdgcn_cvt_pkrtz(bv.z, bv.w);
        __syncthreads();
#pragma unroll
        for (int kp = 0; kp < 4; ++kp) {
            h2_t __attribute__((aligned(16))) a2[8], b2[8];
            *(uint4*)&a2[0] = *(const uint4*)&As2[kp][tr * 8];
            *(uint4*)&a2[4] = *(const uint4*)&As2[kp][tr * 8 + 4];
            *(uint4*)&b2[0] = *(const uint4*)&Bs2[kp][tc * 8];
            *(uint4*)&b2[4] = *(const uint4*)&Bs2[kp][tc * 8 + 4];
#pragma unroll
            for (int i = 0; i < 8; ++i)
#pragma unroll
                for (int j = 0; j < 8; ++j)
                    acc[i][j] = __builtin_amdgcn_fdot2(a2[i], b2[j], acc[i][j], false);
        }
    }
#pragma unroll
    for (int i = 0; i < 8; ++i) {
        const int n  = ntile * 128 + tr * 8 + i;
        const int b_ = n >> 9, t_ = n & 511;
        float* dst = xp + ((size_t)(t_ * BB + b_)) * G4 + colbase + tc * 8;
#pragma unroll
        for (int j = 0; j < 8; ++j) dst[j] = acc[i][j] + bias[colbase + tc * 8 + j];
    }
}

// ---------------------------------------------------------------------------
// K2: LSTM scan v6. 64 blocks = (dir, sample), 512 threads.
// Thread (u=tid>>2, ks=tid&3), f16 dot2, weights resident (64 VGPRs).
// RAW s_barrier + manual lgkmcnt(0): hout stores and the xq prefetch stay
// in flight across the barrier (no vmcnt(0) drain per step).
// ---------------------------------------------------------------------------
__global__ __launch_bounds__(512)
__attribute__((amdgpu_waves_per_eu(2, 2)))
void k_lstm(
    const float* __restrict__ xpf, const float* __restrict__ xpb,
    const float* __restrict__ Whf, const float* __restrict__ Whb,
    float* __restrict__ hf, float* __restrict__ hb)
{
    // [buf][ks*40 + j] f16 units; per-ks block = 80 B -> conflict-free.
    __shared__ __align__(16) __fp16 hsd[2][160];
    const int tid = threadIdx.x;
    const int dir = blockIdx.x >> 5;
    const int b_  = blockIdx.x & 31;
    const float* xp = dir ? xpb : xpf;
    const float* Wh = dir ? Whb : Whf;
    float* hout = dir ? hb : hf;
    const int ks = tid & 3;          // k-quarter (32 wide) == owned gate id
    const int u  = tid >> 2;         // hidden unit 0..127

    // W_hh[g*128+u][ks*32 .. +31] for g=0..3 as packed half2: 4x16 = 64 VGPRs
    h2_t w2[4][16];
#pragma unroll
    for (int g = 0; g < 4; ++g) {
        const float2* wp = (const float2*)(Wh + (size_t)(g * 128 + u) * HH + ks * 32);
#pragma unroll
        for (int j = 0; j < 16; ++j)
            w2[g][j] = __builtin_amdgcn_cvt_pkrtz(wp[j].x, wp[j].y);
    }

    const float mk0 = (ks == 0) ? 1.f : 0.f;
    const float mk1 = (ks == 1) ? 1.f : 0.f;
    const float mk2 = (ks == 2) ? 1.f : 0.f;
    const float mk3 = (ks == 3) ? 1.f : 0.f;
    // unified gate nonlinearity: val = GC0 + GC1 * rcp(1 + exp(GS * p))
    const bool istanh = (ks == 2);
    const float GS  = istanh ? 2.f : -1.f;
    const float GC0 = istanh ? 1.f : 0.f;
    const float GC1 = istanh ? -2.f : 1.f;

    if (tid < 80) ((unsigned int*)&hsd[0][0])[tid] = 0u;   // zero buffer 0
    float c = 0.f;
    const int t0 = dir ? (TT - 1) : 0;
    const int tstep = dir ? -1 : 1;
    const int xstride = tstep * BB * G4;     // floats per time-step
    const int hstride = tstep * BB * HH;
    const float* xqp = xp + ((long long)t0 * BB + b_) * G4 + ks * 128 + u;
    float*       hop = hout + ((long long)t0 * BB + b_) * HH + u;
    float xq = *xqp;
    __syncthreads();

    for (int s = 0; s < TT; ++s) {
        const int rb = s & 1;
        float p0 = mk0 * xq, p1 = mk1 * xq, p2 = mk2 * xq, p3 = mk3 * xq;
        // prefetch next xp now (one-past-end lands in adjacent ws buffer)
        xqp += xstride;
        xq = *xqp;
#pragma unroll
        for (int q = 0; q < 4; ++q) {
            const uint4 hv = *(const uint4*)&hsd[rb][ks * 40 + q * 8];
            const h2_t ha  = __builtin_bit_cast(h2_t, hv.x);
            const h2_t hbv = __builtin_bit_cast(h2_t, hv.y);
            const h2_t hc  = __builtin_bit_cast(h2_t, hv.z);
            const h2_t hd  = __builtin_bit_cast(h2_t, hv.w);
            p0 = __builtin_amdgcn_fdot2(ha,  w2[0][q*4+0], p0, false);
            p0 = __builtin_amdgcn_fdot2(hbv, w2[0][q*4+1], p0, false);
            p0 = __builtin_amdgcn_fdot2(hc,  w2[0][q*4+2], p0, false);
            p0 = __builtin_amdgcn_fdot2(hd,  w2[0][q*4+3], p0, false);
            p1 = __builtin_amdgcn_fdot2(ha,  w2[1][q*4+0], p1, false);
            p1 = __builtin_amdgcn_fdot2(hbv, w2[1][q*4+1], p1, false);
            p1 = __builtin_amdgcn_fdot2(hc,  w2[1][q*4+2], p1, false);
            p1 = __builtin_amdgcn_fdot2(hd,  w2[1][q*4+3], p1, false);
            p2 = __builtin_amdgcn_fdot2(ha,  w2[2][q*4+0], p2, false);
            p2 = __builtin_amdgcn_fdot2(hbv, w2[2][q*4+1], p2, false);
            p2 = __builtin_amdgcn_fdot2(hc,  w2[2][q*4+2], p2, false);
            p2 = __builtin_amdgcn_fdot2(hd,  w2[2][q*4+3], p2, false);
            p3 = __builtin_amdgcn_fdot2(ha,  w2[3][q*4+0], p3, false);
            p3 = __builtin_amdgcn_fdot2(hbv, w2[3][q*4+1], p3, false);
            p3 = __builtin_amdgcn_fdot2(hc,  w2[3][q*4+2], p3, false);
            p3 = __builtin_amdgcn_fdot2(hd,  w2[3][q*4+3], p3, false);
        }
        // quad butterfly: every lane ends with ALL four complete gate sums
        p0 += qxor1(p0); p0 += qxor2(p0);
        p1 += qxor1(p1); p1 += qxor2(p1);
        p2 += qxor1(p2); p2 += qxor2(p2);
        p3 += qxor1(p3); p3 += qxor2(p3);
        // lane ks computes only its gate's nonlinearity, quad_perm regather
        const float psel = p0 * mk0 + p1 * mk1 + p2 * mk2 + p3 * mk3;
        const float val  = GC0 + GC1 * __builtin_amdgcn_rcpf(1.f + __expf(GS * psel));
        const float gi = qbcast(val, 0);
        const float gf = qbcast(val, 1);
        const float gg = qbcast(val, 2);
        const float go = qbcast(val, 3);
        c = gf * c + gi * gg;
        const float tc = 1.f - 2.f * __builtin_amdgcn_rcpf(1.f + __expf(2.f * c));
        const float hv = go * tc;
        if (ks == 0) {
            hsd[rb ^ 1][(u >> 5) * 40 + (u & 31)] = (__fp16)hv;
            *hop = hv;
        }
        hop += hstride;
        // raw barrier: order ONLY the LDS h-write (lgkm), leave the global
        // store + prefetch load in flight (no vmcnt drain).
        asm volatile("s_waitcnt lgkmcnt(0)" ::: "memory");
        __builtin_amdgcn_s_barrier();
        asm volatile("" ::: "memory");
    }
}

// ---------------------------------------------------------------------------
// K3: emit[t][b][l] = (concat(hf,hb)[t][b][:] . W_out[l,:] + b_out[l]) * mask
// ---------------------------------------------------------------------------
__global__ __launch_bounds__(1024) void k_emit(
    const float* __restrict__ hf, const float* __restrict__ hb,
    const float* __restrict__ Wout, const float* __restrict__ bout,
    const int* __restrict__ charr, float* __restrict__ emit)
{
    __shared__ __align__(16) float hsm[BB * 256];
    __shared__ __align__(16) float wsm[LL * 260];
    const int t = blockIdx.x;
    const int tid = threadIdx.x;
    for (int idx = tid; idx < BB * 256; idx += 1024) {
        const int b_ = idx >> 8, u = idx & 255;
        hsm[idx] = (u < HH) ? hf[((size_t)t * BB + b_) * HH + u]
                            : hb[((size_t)t * BB + b_) * HH + (u - HH)];
    }
    for (int idx = tid; idx < LL * 256; idx += 1024) {
        const int l = idx >> 8, u = idx & 255;
        wsm[l * 260 + u] = Wout[idx];
    }
    __syncthreads();
    const int b_ = tid >> 5, l = tid & 31;
    float acc = bout[l];
#pragma unroll 8
    for (int q = 0; q < 64; ++q) {
        const float4 h4 = *(const float4*)&hsm[b_ * 256 + q * 4];
        const float4 w4 = *(const float4*)&wsm[l * 260 + q * 4];
        acc += h4.x * w4.x + h4.y * w4.y + h4.z * w4.z + h4.w * w4.w;
    }
    const float m = (charr[b_ * TT + t] > 0) ? 1.f : 0.f;
    emit[((size_t)t * BB + b_) * LL + l] = acc * m;
}

// ---------------------------------------------------------------------------
// K4: CRF forward v2 — LINEAR-space with periodic renorm.
// ---------------------------------------------------------------------------
__global__ __launch_bounds__(64) void k_crf(
    const float* __restrict__ emit, const int* __restrict__ charr,
    const float* __restrict__ trans, const float* __restrict__ startv,
    const float* __restrict__ endv, float* __restrict__ logZ)
{
    const int tid = threadIdx.x;             // lanes 32..63 mirror lanes 0..31
    const int b_ = blockIdx.x;
    const int j = tid & 31;
    float et[32];
#pragma unroll
    for (int i = 0; i < 32; ++i) et[i] = __expf(trans[i * LL + j]);

    const float a0 = startv[j] + emit[(size_t)b_ * LL + j];
    float M = a0;
    M = fmaxf(M, __shfl_xor(M, 16));
    M = fmaxf(M, __shfl_xor(M, 8));
    M = fmaxf(M, __shfl_xor(M, 4));
    M = fmaxf(M, __shfl_xor(M, 2));
    M = fmaxf(M, __shfl_xor(M, 1));
    float A = __expf(a0 - M);
    float logsc = M;

    float e_nx = emit[((size_t)1 * BB + b_) * LL + j];
    int   m_nx = charr[b_ * TT + 1];

    for (int t = 1; t < TT; ++t) {
        const float ee = __expf(e_nx);       // off critical chain (prefetched)
        const int m_cur = m_nx;
        if (t + 1 < TT) {
            e_nx = emit[((size_t)(t + 1) * BB + b_) * LL + j];
            m_nx = charr[b_ * TT + t + 1];
        }
        float s0 = 0.f, s1 = 0.f, s2 = 0.f, s3 = 0.f;
#pragma unroll
        for (int i = 0; i < 32; i += 4) {
            s0 = fmaf(__shfl(A, i    ), et[i    ], s0);
            s1 = fmaf(__shfl(A, i + 1), et[i + 1], s1);
            s2 = fmaf(__shfl(A, i + 2), et[i + 2], s2);
            s3 = fmaf(__shfl(A, i + 3), et[i + 3], s3);
        }
        const float Anew = ((s0 + s1) + (s2 + s3)) * ee;
        A = (m_cur > 0) ? Anew : A;
        if ((t & 7) == 0) {                  // renorm every 8 steps
            float S = A;
            S = fmaxf(S, __shfl_xor(S, 16));
            S = fmaxf(S, __shfl_xor(S, 8));
            S = fmaxf(S, __shfl_xor(S, 4));
            S = fmaxf(S, __shfl_xor(S, 2));
            S = fmaxf(S, __shfl_xor(S, 1));
            A *= __builtin_amdgcn_rcpf(S);
            logsc += __logf(S);
        }
    }
    // finalize: alpha_j = log(A_j) + logsc; logZ = LSE_j(alpha_j + end_j)
    const float z = __logf(A) + logsc + endv[j];
    float Mz = z;
    Mz = fmaxf(Mz, __shfl_xor(Mz, 16));
    Mz = fmaxf(Mz, __shfl_xor(Mz, 8));
    Mz = fmaxf(Mz, __shfl_xor(Mz, 4));
    Mz = fmaxf(Mz, __shfl_xor(Mz, 2));
    Mz = fmaxf(Mz, __shfl_xor(Mz, 1));
    float sz = __expf(z - Mz);
    sz += __shfl_xor(sz, 16);
    sz += __shfl_xor(sz, 8);
    sz += __shfl_xor(sz, 4);
    sz += __shfl_xor(sz, 2);
    sz += __shfl_xor(sz, 1);
    if (tid == 0) logZ[b_] = Mz + __logf(sz);
}

// ---------------------------------------------------------------------------
// K5: gold path score + final output scalar.
// ---------------------------------------------------------------------------
__global__ __launch_bounds__(1024) void k_gold(
    const float* __restrict__ emit, const int* __restrict__ charr,
    const int* __restrict__ y, const float* __restrict__ trans,
    const float* __restrict__ startv, const float* __restrict__ endv,
    const float* __restrict__ logZ, float* __restrict__ out)
{
    __shared__ float red[BB];
    const int tid = threadIdx.x;
    const int b_ = tid >> 5, l = tid & 31;
    float sc = 0.f;
    int ms = 0;
    for (int t = l; t < TT; t += 32) {
        const int yv = y[b_ * TT + t];
        const int m = (charr[b_ * TT + t] > 0);
        if (m) { sc += emit[((size_t)t * BB + b_) * LL + yv]; ms++; }
        if (t + 1 < TT) {
            const int mn = (charr[b_ * TT + t + 1] > 0);
            if (mn) sc += trans[yv * LL + y[b_ * TT + t + 1]];
        }
    }
#pragma unroll
    for (int o = 16; o; o >>= 1) {
        sc += __shfl_xor(sc, o);
        ms += __shfl_xor(ms, o);
    }
    if (l == 0) {
        int last = ms - 1;
        if (last < 0) last = 0;
        const float gold = startv[y[b_ * TT]] + sc + endv[y[b_ * TT + last]];
        red[b_] = logZ[b_] - gold;
    }
    __syncthreads();
    if (tid == 0) {
        float tot = 0.f;
#pragma unroll
        for (int i = 0; i < BB; ++i) tot += red[i];
        out[0] = tot;
    }
}

extern "C" void kernel_launch(void* const* d_in, const int* in_sizes, int n_in,
                              void* d_out, int out_size, void* d_ws, size_t ws_size,
                              hipStream_t stream) {
    (void)in_sizes; (void)n_in; (void)out_size; (void)ws_size;
    const int*   word  = (const int*)d_in[0];
    const int*   charr = (const int*)d_in[1];
    const int*   yv    = (const int*)d_in[2];
    const float* wemb  = (const float*)d_in[3];
    const float* cemb  = (const float*)d_in[4];
    const float* Wihf  = (const float*)d_in[5];
    const float* Whhf  = (const float*)d_in[6];
    const float* bf    = (const float*)d_in[7];
    const float* Wihb  = (const float*)d_in[8];
    const float* Whhb  = (const float*)d_in[9];
    const float* bb    = (const float*)d_in[10];
    const float* Wout  = (const float*)d_in[11];
    const float* bout  = (const float*)d_in[12];
    const float* trans = (const float*)d_in[13];
    const float* startv= (const float*)d_in[14];
    const float* endv  = (const float*)d_in[15];

    float* ws   = (float*)d_ws;
    float* xpf  = ws;                       // [T][B][512]
    float* xpb  = xpf + (size_t)TT * BB * G4;
    float* hf   = xpb + (size_t)TT * BB * G4;   // [T][B][128]
    float* hb   = hf + (size_t)TT * BB * HH;
    float* emit = hb + (size_t)TT * BB * HH;    // [T][B][32]
    float* logZ = emit + (size_t)TT * BB * LL;  // [32]

    k_inproj<<<dim3(128, 8), 256, 0, stream>>>(word, charr, wemb, cemb,
                                               Wihf, bf, Wihb, bb, xpf, xpb);
    k_lstm<<<64, 512, 0, stream>>>(xpf, xpb, Whhf, Whhb, hf, hb);
    k_emit<<<TT, 1024, 0, stream>>>(hf, hb, Wout, bout, charr, emit);
    k_crf<<<32, 64, 0, stream>>>(emit, charr, trans, startv, endv, logZ);
    k_gold<<<1, 1024, 0, stream>>>(emit, charr, yv, trans, startv, endv, logZ,
                                   (float*)d_out);
}

// Round 7
// 537.119 us; speedup vs baseline: 2.2240x; 1.0037x over previous
//
#include <hip/hip_runtime.h>
#include <math.h>

#define BB 32
#define TT 512
#define DW 128
#define DC 64
#define DD 192
#define HH 128
#define G4 512
#define LL 32

typedef __fp16 h2_t __attribute__((ext_vector_type(2)));

// quad_perm lane-xor via DPP (VALU, not LDS)
__device__ __forceinline__ float qxor1(float x) {
    return __int_as_float(__builtin_amdgcn_update_dpp(0, __float_as_int(x), 0xB1, 0xF, 0xF, true));
}
__device__ __forceinline__ float qxor2(float x) {
    return __int_as_float(__builtin_amdgcn_update_dpp(0, __float_as_int(x), 0x4E, 0xF, 0xF, true));
}
// quad_perm broadcast of lane q (within each quad)
__device__ __forceinline__ float qbcast(float x, int ctrl_imm) {
    switch (ctrl_imm) {
        case 0: return __int_as_float(__builtin_amdgcn_update_dpp(0, __float_as_int(x), 0x00, 0xF, 0xF, true));
        case 1: return __int_as_float(__builtin_amdgcn_update_dpp(0, __float_as_int(x), 0x55, 0xF, 0xF, true));
        case 2: return __int_as_float(__builtin_amdgcn_update_dpp(0, __float_as_int(x), 0xAA, 0xF, 0xF, true));
        default:return __int_as_float(__builtin_amdgcn_update_dpp(0, __float_as_int(x), 0xFF, 0xF, 0xF, true));
    }
}

// ---------------------------------------------------------------------------
// K1: fused embedding-gather + input projection GEMM, f16 dot2 inner loop.
// ---------------------------------------------------------------------------
__global__ __launch_bounds__(256) void k_inproj(
    const int* __restrict__ word, const int* __restrict__ charr,
    const float* __restrict__ wemb, const float* __restrict__ cemb,
    const float* __restrict__ Wf, const float* __restrict__ bf,
    const float* __restrict__ Wb, const float* __restrict__ bb,
    float* __restrict__ xpf, float* __restrict__ xpb)
{
    __shared__ __align__(16) h2_t As2[4][132];   // [k-pair][row]
    __shared__ __align__(16) h2_t Bs2[4][132];   // [k-pair][gate-col]
    const int tid = threadIdx.x;
    const int ntile = blockIdx.x;
    const int ctile = blockIdx.y;
    const int dir = ctile >> 2;
    const float* W = dir ? Wb : Wf;
    const float* bias = dir ? bb : bf;
    float* xp = dir ? xpb : xpf;
    const int colbase = (ctile & 3) * 128;

    const int tr = tid >> 4;    // 0..15
    const int tc = tid & 15;    // 0..15

    float acc[8][8];
#pragma unroll
    for (int i = 0; i < 8; ++i)
#pragma unroll
        for (int j = 0; j < 8; ++j) acc[i][j] = 0.f;

    const int lrow = tid >> 1;            // 0..127
    const int lk   = (tid & 1) * 4;       // 0 or 4
    const int kp0  = lk >> 1;             // 0 or 2
    const int nA   = ntile * 128 + lrow;
    const int wi   = word[nA];
    const int ci   = charr[nA];
    const int g    = colbase + lrow;

    for (int kc = 0; kc < 24; ++kc) {
        const int k0 = kc * 8 + lk;
        float4 av;
        if (k0 < DW) av = *(const float4*)(wemb + (size_t)wi * DW + k0);
        else         av = *(const float4*)(cemb + (size_t)ci * DC + (k0 - DW));
        const float4 bv = *(const float4*)(W + (size_t)g * DD + k0);
        __syncthreads();
        As2[kp0 + 0][lrow] = __builtin_amdgcn_cvt_pkrtz(av.x, av.y);
        As2[kp0 + 1][lrow] = __builtin_amdgcn_cvt_pkrtz(av.z, av.w);
        Bs2[kp0 + 0][lrow] = __builtin_amdgcn_cvt_pkrtz(bv.x, bv.y);
        Bs2[kp0 + 1][lrow] = __builtin_amdgcn_cvt_pkrtz(bv.z, bv.w);
        __syncthreads();
#pragma unroll
        for (int kp = 0; kp < 4; ++kp) {
            h2_t __attribute__((aligned(16))) a2[8], b2[8];
            *(uint4*)&a2[0] = *(const uint4*)&As2[kp][tr * 8];
            *(uint4*)&a2[4] = *(const uint4*)&As2[kp][tr * 8 + 4];
            *(uint4*)&b2[0] = *(const uint4*)&Bs2[kp][tc * 8];
            *(uint4*)&b2[4] = *(const uint4*)&Bs2[kp][tc * 8 + 4];
#pragma unroll
            for (int i = 0; i < 8; ++i)
#pragma unroll
                for (int j = 0; j < 8; ++j)
                    acc[i][j] = __builtin_amdgcn_fdot2(a2[i], b2[j], acc[i][j], false);
        }
    }
#pragma unroll
    for (int i = 0; i < 8; ++i) {
        const int n  = ntile * 128 + tr * 8 + i;
        const int b_ = n >> 9, t_ = n & 511;
        float* dst = xp + ((size_t)(t_ * BB + b_)) * G4 + colbase + tc * 8;
#pragma unroll
        for (int j = 0; j < 8; ++j) dst[j] = acc[i][j] + bias[colbase + tc * 8 + j];
    }
}

// ---------------------------------------------------------------------------
// K2: LSTM scan v7. 64 blocks = (dir, sample), 512 threads.
// Thread (u=tid>>2, ks=tid&3), f16 dot2, weights resident (64 VGPRs).
// Barrier with NO memory-clobber asm anywhere: clobber-free
// "s_waitcnt lgkmcnt(0)" pinned by sched_barrier(0) + raw s_barrier.
// The waitcnt pass has no reason to drain vmcnt -> hout stores and the xq
// prefetch stay in flight across the barrier.
// ---------------------------------------------------------------------------
__global__ __launch_bounds__(512)
__attribute__((amdgpu_waves_per_eu(2, 2)))
void k_lstm(
    const float* __restrict__ xpf, const float* __restrict__ xpb,
    const float* __restrict__ Whf, const float* __restrict__ Whb,
    float* __restrict__ hf, float* __restrict__ hb)
{
    // [buf][ks*40 + j] f16 units; per-ks block = 80 B -> conflict-free.
    __shared__ __align__(16) __fp16 hsd[2][160];
    const int tid = threadIdx.x;
    const int dir = blockIdx.x >> 5;
    const int b_  = blockIdx.x & 31;
    const float* xp = dir ? xpb : xpf;
    const float* Wh = dir ? Whb : Whf;
    float* hout = dir ? hb : hf;
    const int ks = tid & 3;          // k-quarter (32 wide) == owned gate id
    const int u  = tid >> 2;         // hidden unit 0..127

    // W_hh[g*128+u][ks*32 .. +31] for g=0..3 as packed half2: 4x16 = 64 VGPRs
    h2_t w2[4][16];
#pragma unroll
    for (int g = 0; g < 4; ++g) {
        const float2* wp = (const float2*)(Wh + (size_t)(g * 128 + u) * HH + ks * 32);
#pragma unroll
        for (int j = 0; j < 16; ++j)
            w2[g][j] = __builtin_amdgcn_cvt_pkrtz(wp[j].x, wp[j].y);
    }

    const float mk0 = (ks == 0) ? 1.f : 0.f;
    const float mk1 = (ks == 1) ? 1.f : 0.f;
    const float mk2 = (ks == 2) ? 1.f : 0.f;
    const float mk3 = (ks == 3) ? 1.f : 0.f;
    // unified gate nonlinearity: val = GC0 + GC1 * rcp(1 + exp(GS * p))
    const bool istanh = (ks == 2);
    const float GS  = istanh ? 2.f : -1.f;
    const float GC0 = istanh ? 1.f : 0.f;
    const float GC1 = istanh ? -2.f : 1.f;
    const bool ks1 = (ks & 1) != 0;
    const bool ks2 = (ks & 2) != 0;

    if (tid < 80) ((unsigned int*)&hsd[0][0])[tid] = 0u;   // zero buffer 0
    float c = 0.f;
    const int t0 = dir ? (TT - 1) : 0;
    const int tstep = dir ? -1 : 1;
    const int xstride = tstep * BB * G4;     // floats per time-step
    const int hstride = tstep * BB * HH;
    const float* xqp = xp + ((long long)t0 * BB + b_) * G4 + ks * 128 + u;
    float*       hop = hout + ((long long)t0 * BB + b_) * HH + u;
    float xq = *xqp;
    __syncthreads();

    for (int s = 0; s < TT; ++s) {
        const int rb = s & 1;
        float p0 = mk0 * xq, p1 = mk1 * xq, p2 = mk2 * xq, p3 = mk3 * xq;
        // prefetch next xp now (one-past-end lands in adjacent ws buffer)
        xqp += xstride;
        xq = *xqp;
#pragma unroll
        for (int q = 0; q < 4; ++q) {
            const uint4 hv = *(const uint4*)&hsd[rb][ks * 40 + q * 8];
            const h2_t ha  = __builtin_bit_cast(h2_t, hv.x);
            const h2_t hbv = __builtin_bit_cast(h2_t, hv.y);
            const h2_t hc  = __builtin_bit_cast(h2_t, hv.z);
            const h2_t hd  = __builtin_bit_cast(h2_t, hv.w);
            p0 = __builtin_amdgcn_fdot2(ha,  w2[0][q*4+0], p0, false);
            p0 = __builtin_amdgcn_fdot2(hbv, w2[0][q*4+1], p0, false);
            p0 = __builtin_amdgcn_fdot2(hc,  w2[0][q*4+2], p0, false);
            p0 = __builtin_amdgcn_fdot2(hd,  w2[0][q*4+3], p0, false);
            p1 = __builtin_amdgcn_fdot2(ha,  w2[1][q*4+0], p1, false);
            p1 = __builtin_amdgcn_fdot2(hbv, w2[1][q*4+1], p1, false);
            p1 = __builtin_amdgcn_fdot2(hc,  w2[1][q*4+2], p1, false);
            p1 = __builtin_amdgcn_fdot2(hd,  w2[1][q*4+3], p1, false);
            p2 = __builtin_amdgcn_fdot2(ha,  w2[2][q*4+0], p2, false);
            p2 = __builtin_amdgcn_fdot2(hbv, w2[2][q*4+1], p2, false);
            p2 = __builtin_amdgcn_fdot2(hc,  w2[2][q*4+2], p2, false);
            p2 = __builtin_amdgcn_fdot2(hd,  w2[2][q*4+3], p2, false);
            p3 = __builtin_amdgcn_fdot2(ha,  w2[3][q*4+0], p3, false);
            p3 = __builtin_amdgcn_fdot2(hbv, w2[3][q*4+1], p3, false);
            p3 = __builtin_amdgcn_fdot2(hc,  w2[3][q*4+2], p3, false);
            p3 = __builtin_amdgcn_fdot2(hd,  w2[3][q*4+3], p3, false);
        }
        // quad butterfly: every lane ends with ALL four complete gate sums
        p0 += qxor1(p0); p0 += qxor2(p0);
        p1 += qxor1(p1); p1 += qxor2(p1);
        p2 += qxor1(p2); p2 += qxor2(p2);
        p3 += qxor1(p3); p3 += qxor2(p3);
        // lane ks computes only its gate's nonlinearity, quad_perm regather
        const float pa   = ks1 ? p1 : p0;
        const float pb   = ks1 ? p3 : p2;
        const float psel = ks2 ? pb : pa;
        const float val  = GC0 + GC1 * __builtin_amdgcn_rcpf(1.f + __expf(GS * psel));
        const float gi = qbcast(val, 0);
        const float gf = qbcast(val, 1);
        const float gg = qbcast(val, 2);
        const float go = qbcast(val, 3);
        c = gf * c + gi * gg;
        const float tc = 1.f - 2.f * __builtin_amdgcn_rcpf(1.f + __expf(2.f * c));
        const float hv = go * tc;
        if (ks == 0) {
            hsd[rb ^ 1][(u >> 5) * 40 + (u & 31)] = (__fp16)hv;
            *hop = hv;
        }
        hop += hstride;
        // raw barrier, NO memory clobber anywhere: order only LDS (lgkm),
        // leave global store + prefetch load in flight.
        __builtin_amdgcn_sched_barrier(0);
        asm volatile("s_waitcnt lgkmcnt(0)");
        __builtin_amdgcn_s_barrier();
        __builtin_amdgcn_sched_barrier(0);
    }
}

// ---------------------------------------------------------------------------
// K3: emit[t][b][l] = (concat(hf,hb)[t][b][:] . W_out[l,:] + b_out[l]) * mask
// ---------------------------------------------------------------------------
__global__ __launch_bounds__(1024) void k_emit(
    const float* __restrict__ hf, const float* __restrict__ hb,
    const float* __restrict__ Wout, const float* __restrict__ bout,
    const int* __restrict__ charr, float* __restrict__ emit)
{
    __shared__ __align__(16) float hsm[BB * 256];
    __shared__ __align__(16) float wsm[LL * 260];
    const int t = blockIdx.x;
    const int tid = threadIdx.x;
    for (int idx = tid; idx < BB * 256; idx += 1024) {
        const int b_ = idx >> 8, u = idx & 255;
        hsm[idx] = (u < HH) ? hf[((size_t)t * BB + b_) * HH + u]
                            : hb[((size_t)t * BB + b_) * HH + (u - HH)];
    }
    for (int idx = tid; idx < LL * 256; idx += 1024) {
        const int l = idx >> 8, u = idx & 255;
        wsm[l * 260 + u] = Wout[idx];
    }
    __syncthreads();
    const int b_ = tid >> 5, l = tid & 31;
    float acc = bout[l];
#pragma unroll 8
    for (int q = 0; q < 64; ++q) {
        const float4 h4 = *(const float4*)&hsm[b_ * 256 + q * 4];
        const float4 w4 = *(const float4*)&wsm[l * 260 + q * 4];
        acc += h4.x * w4.x + h4.y * w4.y + h4.z * w4.z + h4.w * w4.w;
    }
    const float m = (charr[b_ * TT + t] > 0) ? 1.f : 0.f;
    emit[((size_t)t * BB + b_) * LL + l] = acc * m;
}

// ---------------------------------------------------------------------------
// K4: CRF forward v2 — LINEAR-space with periodic renorm.
// ---------------------------------------------------------------------------
__global__ __launch_bounds__(64) void k_crf(
    const float* __restrict__ emit, const int* __restrict__ charr,
    const float* __restrict__ trans, const float* __restrict__ startv,
    const float* __restrict__ endv, float* __restrict__ logZ)
{
    const int tid = threadIdx.x;             // lanes 32..63 mirror lanes 0..31
    const int b_ = blockIdx.x;
    const int j = tid & 31;
    float et[32];
#pragma unroll
    for (int i = 0; i < 32; ++i) et[i] = __expf(trans[i * LL + j]);

    const float a0 = startv[j] + emit[(size_t)b_ * LL + j];
    float M = a0;
    M = fmaxf(M, __shfl_xor(M, 16));
    M = fmaxf(M, __shfl_xor(M, 8));
    M = fmaxf(M, __shfl_xor(M, 4));
    M = fmaxf(M, __shfl_xor(M, 2));
    M = fmaxf(M, __shfl_xor(M, 1));
    float A = __expf(a0 - M);
    float logsc = M;

    float e_nx = emit[((size_t)1 * BB + b_) * LL + j];
    int   m_nx = charr[b_ * TT + 1];

    for (int t = 1; t < TT; ++t) {
        const float ee = __expf(e_nx);       // off critical chain (prefetched)
        const int m_cur = m_nx;
        if (t + 1 < TT) {
            e_nx = emit[((size_t)(t + 1) * BB + b_) * LL + j];
            m_nx = charr[b_ * TT + t + 1];
        }
        float s0 = 0.f, s1 = 0.f, s2 = 0.f, s3 = 0.f;
#pragma unroll
        for (int i = 0; i < 32; i += 4) {
            s0 = fmaf(__shfl(A, i    ), et[i    ], s0);
            s1 = fmaf(__shfl(A, i + 1), et[i + 1], s1);
            s2 = fmaf(__shfl(A, i + 2), et[i + 2], s2);
            s3 = fmaf(__shfl(A, i + 3), et[i + 3], s3);
        }
        const float Anew = ((s0 + s1) + (s2 + s3)) * ee;
        A = (m_cur > 0) ? Anew : A;
        if ((t & 7) == 0) {                  // renorm every 8 steps
            float S = A;
            S = fmaxf(S, __shfl_xor(S, 16));
            S = fmaxf(S, __shfl_xor(S, 8));
            S = fmaxf(S, __shfl_xor(S, 4));
            S = fmaxf(S, __shfl_xor(S, 2));
            S = fmaxf(S, __shfl_xor(S, 1));
            A *= __builtin_amdgcn_rcpf(S);
            logsc += __logf(S);
        }
    }
    // finalize: alpha_j = log(A_j) + logsc; logZ = LSE_j(alpha_j + end_j)
    const float z = __logf(A) + logsc + endv[j];
    float Mz = z;
    Mz = fmaxf(Mz, __shfl_xor(Mz, 16));
    Mz = fmaxf(Mz, __shfl_xor(Mz, 8));
    Mz = fmaxf(Mz, __shfl_xor(Mz, 4));
    Mz = fmaxf(Mz, __shfl_xor(Mz, 2));
    Mz = fmaxf(Mz, __shfl_xor(Mz, 1));
    float sz = __expf(z - Mz);
    sz += __shfl_xor(sz, 16);
    sz += __shfl_xor(sz, 8);
    sz += __shfl_xor(sz, 4);
    sz += __shfl_xor(sz, 2);
    sz += __shfl_xor(sz, 1);
    if (tid == 0) logZ[b_] = Mz + __logf(sz);
}

// ---------------------------------------------------------------------------
// K5: gold path score + final output scalar.
// ---------------------------------------------------------------------------
__global__ __launch_bounds__(1024) void k_gold(
    const float* __restrict__ emit, const int* __restrict__ charr,
    const int* __restrict__ y, const float* __restrict__ trans,
    const float* __restrict__ startv, const float* __restrict__ endv,
    const float* __restrict__ logZ, float* __restrict__ out)
{
    __shared__ float red[BB];
    const int tid = threadIdx.x;
    const int b_ = tid >> 5, l = tid & 31;
    float sc = 0.f;
    int ms = 0;
    for (int t = l; t < TT; t += 32) {
        const int yv = y[b_ * TT + t];
        const int m = (charr[b_ * TT + t] > 0);
        if (m) { sc += emit[((size_t)t * BB + b_) * LL + yv]; ms++; }
        if (t + 1 < TT) {
            const int mn = (charr[b_ * TT + t + 1] > 0);
            if (mn) sc += trans[yv * LL + y[b_ * TT + t + 1]];
        }
    }
#pragma unroll
    for (int o = 16; o; o >>= 1) {
        sc += __shfl_xor(sc, o);
        ms += __shfl_xor(ms, o);
    }
    if (l == 0) {
        int last = ms - 1;
        if (last < 0) last = 0;
        const float gold = startv[y[b_ * TT]] + sc + endv[y[b_ * TT + last]];
        red[b_] = logZ[b_] - gold;
    }
    __syncthreads();
    if (tid == 0) {
        float tot = 0.f;
#pragma unroll
        for (int i = 0; i < BB; ++i) tot += red[i];
        out[0] = tot;
    }
}

extern "C" void kernel_launch(void* const* d_in, const int* in_sizes, int n_in,
                              void* d_out, int out_size, void* d_ws, size_t ws_size,
                              hipStream_t stream) {
    (void)in_sizes; (void)n_in; (void)out_size; (void)ws_size;
    const int*   word  = (const int*)d_in[0];
    const int*   charr = (const int*)d_in[1];
    const int*   yv    = (const int*)d_in[2];
    const float* wemb  = (const float*)d_in[3];
    const float* cemb  = (const float*)d_in[4];
    const float* Wihf  = (const float*)d_in[5];
    const float* Whhf  = (const float*)d_in[6];
    const float* bf    = (const float*)d_in[7];
    const float* Wihb  = (const float*)d_in[8];
    const float* Whhb  = (const float*)d_in[9];
    const float* bb    = (const float*)d_in[10];
    const float* Wout  = (const float*)d_in[11];
    const float* bout  = (const float*)d_in[12];
    const float* trans = (const float*)d_in[13];
    const float* startv= (const float*)d_in[14];
    const float* endv  = (const float*)d_in[15];

    float* ws   = (float*)d_ws;
    float* xpf  = ws;                       // [T][B][512]
    float* xpb  = xpf + (size_t)TT * BB * G4;
    float* hf   = xpb + (size_t)TT * BB * G4;   // [T][B][128]
    float* hb   = hf + (size_t)TT * BB * HH;
    float* emit = hb + (size_t)TT * BB * HH;    // [T][B][32]
    float* logZ = emit + (size_t)TT * BB * LL;  // [32]

    k_inproj<<<dim3(128, 8), 256, 0, stream>>>(word, charr, wemb, cemb,
                                               Wihf, bf, Wihb, bb, xpf, xpb);
    k_lstm<<<64, 512, 0, stream>>>(xpf, xpb, Whhf, Whhb, hf, hb);
    k_emit<<<TT, 1024, 0, stream>>>(hf, hb, Wout, bout, charr, emit);
    k_crf<<<32, 64, 0, stream>>>(emit, charr, trans, startv, endv, logZ);
    k_gold<<<1, 1024, 0, stream>>>(emit, charr, yv, trans, startv, endv, logZ,
                                   (float*)d_out);
}